// Round 8
// baseline (497.445 us; speedup 1.0000x reference)
//
#include <hip/hip_runtime.h>
#include <math.h>

#define B_    4
#define N_    4096
#define DIM_  512
#define H_    8
#define DH_   64
#define M_    256
#define LGRP  16
#define BH_   (B_*H_)
#define SCALE_ 0.125f
#define LN_EPS_ 1e-5f

#define SZ_QKVH (B_*H_*N_*DH_)   /* 8388608 */
#define SZ_LM   (BH_*M_*DH_)     /* 524288  */
#define SZ_MM   (BH_*M_*M_)      /* 2097152 */

typedef unsigned short ushort_t;
typedef __attribute__((ext_vector_type(8))) short bfrag8;
typedef __attribute__((ext_vector_type(4))) float fvec4;

__device__ __forceinline__ ushort_t f2b(float f) {
    unsigned u = __float_as_uint(f);
    unsigned r = (u + 0x7fffu + ((u >> 16) & 1u)) >> 16;
    return (ushort_t)r;
}
__device__ __forceinline__ float b2f(ushort_t s) {
    return __uint_as_float(((unsigned)s) << 16);
}

// async global->LDS DMA, 16B/lane; LDS dest = wave-uniform base + lane*16
__device__ __forceinline__ void gload16(const ushort_t* g, ushort_t* l) {
    __builtin_amdgcn_global_load_lds(
        (const __attribute__((address_space(1))) void*)g,
        (__attribute__((address_space(3))) void*)l, 16, 0, 0);
}

// ---------------- LayerNorm -> bf16 nx ----------------
__global__ __launch_bounds__(256) void ln_kernel(const float* __restrict__ x,
                                                 const float* __restrict__ w,
                                                 const float* __restrict__ bb,
                                                 ushort_t* __restrict__ nxb) {
    int row = blockIdx.x;
    int t = threadIdx.x;
    const float* xr = x + (size_t)row * DIM_;
    float v0 = xr[t], v1 = xr[t + 256];
    float s = v0 + v1, sq = v0 * v0 + v1 * v1;
    __shared__ float ls[4], lq[4];
    for (int off = 32; off > 0; off >>= 1) {
        s  += __shfl_down(s, off);
        sq += __shfl_down(sq, off);
    }
    int wid = t >> 6, lid = t & 63;
    if (lid == 0) { ls[wid] = s; lq[wid] = sq; }
    __syncthreads();
    if (t == 0) {
        float S = 0, Q = 0;
        for (int i = 0; i < 4; i++) { S += ls[i]; Q += lq[i]; }
        ls[0] = S; lq[0] = Q;
    }
    __syncthreads();
    float mean = ls[0] * (1.f / DIM_);
    float var  = lq[0] * (1.f / DIM_) - mean * mean;
    float rs = rsqrtf(var + LN_EPS_);
    ushort_t* o = nxb + (size_t)row * DIM_;
    o[t]       = f2b((v0 - mean) * rs * w[t]       + bb[t]);
    o[t + 256] = f2b((v1 - mean) * rs * w[t + 256] + bb[t + 256]);
}

// ---------------- transpose + cast fp32 [R][C] -> bf16 [C][R] ----------------
__global__ __launch_bounds__(256) void tcast(const float* __restrict__ in,
                                             ushort_t* __restrict__ outT,
                                             int R, int C) {
    __shared__ float tile[32][33];
    int c0 = blockIdx.x * 32, r0 = blockIdx.y * 32;
    int t = threadIdx.x;
    #pragma unroll
    for (int u = 0; u < 4; u++) {
        int lin = t + 256 * u;
        int r = lin >> 5, c = lin & 31;
        tile[r][c] = in[(size_t)(r0 + r) * C + c0 + c];
    }
    __syncthreads();
    #pragma unroll
    for (int u = 0; u < 4; u++) {
        int lin = t + 256 * u;
        int cc = lin >> 5, rr = lin & 31;
        outT[(size_t)(c0 + cc) * R + r0 + rr] = f2b(tile[rr][cc]);
    }
}

// ---------------- big MFMA GEMM: C[M][N] = A[M][512] @ BT[N][512]^T ----------------
// Dbuf global_load_lds + both-sides XOR swizzle + XCD-chunked block swizzle.
// EPI 0: qkv epilogue (bf16 q/k/v, LDS-coalesced). EPI 1: out = omega*x + bo + C.
template<int EPI>
__global__ __launch_bounds__(256) void gemm_bt128(const ushort_t* __restrict__ A,
                                                  const ushort_t* __restrict__ BT,
                                                  ushort_t* __restrict__ qb,
                                                  ushort_t* __restrict__ kb,
                                                  ushort_t* __restrict__ vb,
                                                  const float* __restrict__ x,
                                                  const float* __restrict__ bo,
                                                  const float* __restrict__ omega,
                                                  float* __restrict__ out) {
    const int K = 512;
    __shared__ __align__(16) ushort_t smem[4 * 128 * 64];   // 2 bufs x (A+B 128x64) = 64 KB
    int t = threadIdx.x;
    int lin = blockIdx.x + blockIdx.y * gridDim.x;
    int nwg = gridDim.x * gridDim.y;
    int wg  = (lin & 7) * (nwg >> 3) + (lin >> 3);
    int n0 = (wg % gridDim.x) * 128, m0 = (wg / gridDim.x) * 128;
    int w = t >> 6, lane = t & 63;
    int wr = (w >> 1) * 64, wc = (w & 1) * 64;
    int l15 = lane & 15, quad = lane >> 4, kq = quad * 8;
    int lrow = lane >> 3, lc8 = (lane & 7) * 8;
    int scol = lc8 ^ ((lrow & 7) << 3);     // source-side swizzle (elems)
    int sw   = (l15 & 7) << 3;              // read-side swizzle: row&7 == l15&7
    fvec4 acc[4][4] = {};

    auto stage = [&](int buf, int kc) {
        ushort_t* Ad = smem + buf * 16384;
        ushort_t* Bd = Ad + 8192;
        #pragma unroll
        for (int u = 0; u < 4; u++) {
            int r0 = (w << 5) + (u << 3);
            int row = r0 + lrow;
            const ushort_t* ga;
            if (EPI == 0) {
                ga = A + (size_t)(m0 + row) * K + kc + scol;
            } else {
                int grow = m0 + row; int b_ = grow >> 12, nn = grow & 4095;
                ga = A + (((size_t)(b_ * H_ + (kc >> 6)) * N_ + nn) << 6) + scol;
            }
            gload16(ga, Ad + r0 * 64);
            gload16(BT + (size_t)(n0 + row) * K + kc + scol, Bd + r0 * 64);
        }
    };

    stage(0, 0);
    __syncthreads();
    int cur = 0;
    for (int kt = 0; kt < 8; ++kt) {
        if (kt < 7) stage(cur ^ 1, (kt + 1) * 64);
        const ushort_t* As = smem + cur * 16384;
        const ushort_t* Bs = As + 8192;
        #pragma unroll
        for (int ks = 0; ks < 64; ks += 32) {
            int kcol = (ks + kq) ^ sw;
            bfrag8 a[4], b[4];
            #pragma unroll
            for (int r = 0; r < 4; r++) a[r] = *(bfrag8*)(As + (wr + r * 16 + l15) * 64 + kcol);
            #pragma unroll
            for (int c = 0; c < 4; c++) b[c] = *(bfrag8*)(Bs + (wc + c * 16 + l15) * 64 + kcol);
            #pragma unroll
            for (int r = 0; r < 4; r++)
                #pragma unroll
                for (int c = 0; c < 4; c++)
                    acc[r][c] = __builtin_amdgcn_mfma_f32_16x16x32_bf16(a[r], b[c], acc[r][c], 0, 0, 0);
        }
        __syncthreads();
        cur ^= 1;
    }

    if (EPI == 0) {
        int sec = n0 >> 9;                     // 0=q 1=k 2=v (tile never crosses)
        float mul = (sec == 0) ? SCALE_ : 1.0f;
        ushort_t (*Ct)[132] = (ushort_t(*)[132])smem;
        #pragma unroll
        for (int r = 0; r < 4; r++) {
            #pragma unroll
            for (int reg = 0; reg < 4; reg++) {
                int lr = wr + r * 16 + quad * 4 + reg;
                #pragma unroll
                for (int c = 0; c < 4; c++) {
                    int lc = wc + c * 16 + l15;
                    Ct[lr][lc] = f2b(acc[r][c][reg] * mul);
                }
            }
        }
        __syncthreads();
        int row = t & 127, half = t >> 7;
        int grow = m0 + row; int b_ = grow >> 12, nn = grow & 4095;
        int head = ((n0 & 511) >> 6) + half;
        ushort_t* dstbuf = (sec == 0) ? qb : ((sec == 1) ? kb : vb);
        ushort_t* dp = dstbuf + (((size_t)(b_ * H_ + head) * N_ + nn) << 6);
        #pragma unroll
        for (int i = 0; i < 8; i++)
            *(uint4*)(dp + i * 8) = *(uint4*)&Ct[row][half * 64 + i * 8];
    } else {
        float om = omega[0];
        #pragma unroll
        for (int r = 0; r < 4; r++) {
            #pragma unroll
            for (int reg = 0; reg < 4; reg++) {
                int grow = m0 + wr + r * 16 + quad * 4 + reg;
                #pragma unroll
                for (int c = 0; c < 4; c++) {
                    int gcol = n0 + wc + c * 16 + l15;
                    size_t o = (size_t)grow * DIM_ + gcol;
                    out[o] = om * x[o] + bo[gcol] + acc[r][c][reg];
                }
            }
        }
    }
}

// ---------------- landmark means (bf16 in/out, uint4 vectorized) ----------------
__global__ __launch_bounds__(256) void landmark_kernel(const ushort_t* __restrict__ q,
                                                       const ushort_t* __restrict__ k,
                                                       ushort_t* __restrict__ ql,
                                                       ushort_t* __restrict__ kl) {
    int idx = blockIdx.x * 256 + threadIdx.x;    // over SZ_LM/8 = 65536
    const ushort_t* src = blockIdx.y ? k : q;
    ushort_t* dst = blockIdx.y ? kl : ql;
    int d8 = (idx & 7) * 8;
    int m = (idx >> 3) & 255;
    int bh = idx >> 11;
    const ushort_t* p = src + (((size_t)bh * N_) + m * LGRP) * DH_ + d8;
    float s[8] = {};
    #pragma unroll
    for (int j = 0; j < LGRP; j++) {
        union { uint4 u4; ushort_t sv[8]; } val;
        val.u4 = *(const uint4*)(p + (size_t)j * DH_);
        #pragma unroll
        for (int e = 0; e < 8; e++) s[e] += b2f(val.sv[e]);
    }
    union { uint4 u4; ushort_t sv[8]; } o;
    #pragma unroll
    for (int e = 0; e < 8; e++) o.sv[e] = f2b(s[e] * (1.f / LGRP));
    *(uint4*)(dst + ((size_t)bh * M_ + m) * DH_ + d8) = o.u4;
}

// ---------------- sim2 + softmax -> a2 (fp32 + bf16) ----------------
__global__ __launch_bounds__(256) void sim2_softmax(const ushort_t* __restrict__ ql,
                                                    const ushort_t* __restrict__ kl,
                                                    float* __restrict__ a2,
                                                    ushort_t* __restrict__ a2b) {
    int i = blockIdx.x, bh = blockIdx.y, j = threadIdx.x;
    __shared__ float qrow[64];
    __shared__ float red[256];
    if (j < 64) qrow[j] = b2f(ql[((size_t)bh * M_ + i) * DH_ + j]);
    __syncthreads();
    const ushort_t* kr = kl + ((size_t)bh * M_ + j) * DH_;
    float s = 0;
    #pragma unroll
    for (int d = 0; d < 64; d++) s += qrow[d] * b2f(kr[d]);
    red[j] = s; __syncthreads();
    for (int off = 128; off > 0; off >>= 1) {
        if (j < off) red[j] = fmaxf(red[j], red[j + off]);
        __syncthreads();
    }
    float mx = red[0]; __syncthreads();
    float p = __expf(s - mx);
    red[j] = p; __syncthreads();
    for (int off = 128; off > 0; off >>= 1) {
        if (j < off) red[j] += red[j + off];
        __syncthreads();
    }
    float res = p / red[0];
    size_t o = ((size_t)bh * M_ + i) * M_ + j;
    a2[o] = res;
    a2b[o] = f2b(res);
}

// ---------------- pinv init scale: column sums (row sums of softmax == 1) ----------------
__global__ void zero2(unsigned* p) { if (threadIdx.x < 2) p[threadIdx.x] = 0u; }

__global__ __launch_bounds__(256) void colpart(const float* __restrict__ a2,
                                               float* __restrict__ cs2) {
    int bh = blockIdx.x, s = blockIdx.y, t = threadIdx.x;
    const float* A = a2 + ((size_t)bh << 16) + (size_t)s * 32 * M_;
    float cs = 0.f;
    #pragma unroll
    for (int i = 0; i < 32; i++) cs += A[(size_t)i * M_ + t];
    cs2[((size_t)s * BH_ + bh) * M_ + t] = cs;
}

__global__ __launch_bounds__(256) void colmax(const float* __restrict__ cs2, unsigned* red) {
    int bh = blockIdx.x, t = threadIdx.x;
    float v = 0.f;
    #pragma unroll
    for (int s = 0; s < 8; s++) v += cs2[((size_t)s * BH_ + bh) * M_ + t];
    __shared__ float lr[256];
    lr[t] = v; __syncthreads();
    for (int off = 128; off > 0; off >>= 1) {
        if (t < off) lr[t] = fmaxf(lr[t], lr[t + off]);
        __syncthreads();
    }
    if (t == 0) atomicMax(red, __float_as_uint(lr[0]));
}

__global__ __launch_bounds__(256) void pinv_init2(const float* __restrict__ a2,
                                                  const unsigned* __restrict__ red,
                                                  ushort_t* __restrict__ zA,
                                                  ushort_t* __restrict__ zAT) {
    __shared__ float tile[32][33];
    int bt = blockIdx.z; int j0 = blockIdx.x * 32, i0 = blockIdx.y * 32;
    float invd = 1.f / __uint_as_float(red[0]);
    const float* Ab = a2 + ((size_t)bt << 16);
    size_t bo = (size_t)bt << 16;
    int t = threadIdx.x;
    #pragma unroll
    for (int u = 0; u < 4; u++) {
        int lin = t + 256 * u; int r = lin >> 5, c = lin & 31;
        float vv = Ab[(size_t)(i0 + r) * M_ + j0 + c] * invd;
        tile[r][c] = vv;
        zAT[bo + (size_t)(i0 + r) * M_ + j0 + c] = f2b(vv);
    }
    __syncthreads();
    #pragma unroll
    for (int u = 0; u < 4; u++) {
        int lin = t + 256 * u; int cc = lin >> 5, rr = lin & 31;
        zA[bo + (size_t)(j0 + cc) * M_ + i0 + rr] = f2b(tile[rr][cc]);
    }
}

// ---------------- batched 256^3 MFMA gemm (64x64 tile, dbuf gload_lds + swizzle) ----------------
__global__ __launch_bounds__(256) void gemm_pinv(const ushort_t* __restrict__ A,
                                                 const ushort_t* __restrict__ BT,
                                                 ushort_t* __restrict__ outN,
                                                 ushort_t* __restrict__ outT,
                                                 ushort_t* __restrict__ outT1,
                                                 float* __restrict__ outF,
                                                 float coefI, float scale) {
    __shared__ __align__(16) ushort_t smem[2 * 8192];   // 2 bufs x (A+B 64x64) = 32 KB
    int t = threadIdx.x;
    int lin = blockIdx.x + (blockIdx.y << 2) + (blockIdx.z << 4);
    int wg  = (lin & 7) * 64 + (lin >> 3);
    int n0 = (wg & 3) * 64, m0 = ((wg >> 2) & 3) * 64;
    int bt = wg >> 4;
    const ushort_t* Ab = A + ((size_t)bt << 16);
    const ushort_t* Bb = BT + ((size_t)bt << 16);
    int w = t >> 6, lane = t & 63;
    int wr = (w >> 1) * 32, wc = (w & 1) * 32;
    int l15 = lane & 15, quad = lane >> 4, kq = quad * 8;
    int lrow = lane >> 3, lc8 = (lane & 7) * 8;
    int scol = lc8 ^ ((lrow & 7) << 3);
    int sw   = (l15 & 7) << 3;
    fvec4 acc[2][2] = {};

    auto stage = [&](int buf, int kc) {
        ushort_t* Ad = smem + buf * 8192;
        ushort_t* Bd = Ad + 4096;
        #pragma unroll
        for (int u = 0; u < 2; u++) {
            int r0 = (w << 4) + (u << 3);
            int row = r0 + lrow;
            gload16(Ab + (size_t)(m0 + row) * M_ + kc + scol, Ad + r0 * 64);
            gload16(Bb + (size_t)(n0 + row) * M_ + kc + scol, Bd + r0 * 64);
        }
    };

    stage(0, 0);
    __syncthreads();
    int cur = 0;
    for (int kt = 0; kt < 4; ++kt) {
        if (kt < 3) stage(cur ^ 1, (kt + 1) * 64);
        const ushort_t* As = smem + cur * 8192;
        const ushort_t* Bs = As + 4096;
        #pragma unroll
        for (int ks = 0; ks < 64; ks += 32) {
            int kcol = (ks + kq) ^ sw;
            bfrag8 a[2], b[2];
            #pragma unroll
            for (int r = 0; r < 2; r++) a[r] = *(bfrag8*)(As + (wr + r * 16 + l15) * 64 + kcol);
            #pragma unroll
            for (int c = 0; c < 2; c++) b[c] = *(bfrag8*)(Bs + (wc + c * 16 + l15) * 64 + kcol);
            #pragma unroll
            for (int r = 0; r < 2; r++)
                #pragma unroll
                for (int c = 0; c < 2; c++)
                    acc[r][c] = __builtin_amdgcn_mfma_f32_16x16x32_bf16(a[r], b[c], acc[r][c], 0, 0, 0);
        }
        __syncthreads();
        cur ^= 1;
    }

    size_t bto = (size_t)bt << 16;
    if (outN || outF) {
        #pragma unroll
        for (int r = 0; r < 2; r++) {
            #pragma unroll
            for (int reg = 0; reg < 4; reg++) {
                int grow = m0 + wr + r * 16 + quad * 4 + reg;
                #pragma unroll
                for (int c = 0; c < 2; c++) {
                    int gcol = n0 + wc + c * 16 + l15;
                    float cv = scale * acc[r][c][reg] + (grow == gcol ? coefI : 0.f);
                    if (outN) outN[bto + (size_t)grow * M_ + gcol] = f2b(cv);
                    if (outF) outF[bto + (size_t)grow * M_ + gcol] = cv;
                }
            }
        }
    }
    if (outT || outT1) {
        ushort_t (*Ct)[65] = (ushort_t(*)[65])&smem[0];
        #pragma unroll
        for (int r = 0; r < 2; r++) {
            #pragma unroll
            for (int reg = 0; reg < 4; reg++) {
                int lr = wr + r * 16 + quad * 4 + reg;
                #pragma unroll
                for (int c = 0; c < 2; c++) {
                    int lc = wc + c * 16 + l15;
                    float cv = scale * acc[r][c][reg] + ((m0 + lr) == (n0 + lc) ? coefI : 0.f);
                    Ct[lr][lc] = f2b(cv);
                }
            }
        }
        __syncthreads();
        int j = t & 63, quarter = t >> 6, i0 = quarter * 16;
        #pragma unroll
        for (int vq = 0; vq < 2; vq++) {
            union { uint4 u4; ushort_t s[8]; } o1, o2;
            #pragma unroll
            for (int e = 0; e < 8; e++) {
                int il = i0 + vq * 8 + e;
                ushort_t bv = Ct[il][j];
                o1.s[e] = bv;
                o2.s[e] = f2b(((m0 + il) == (n0 + j) ? 7.f : 0.f) - b2f(bv));
            }
            size_t dst = bto + (size_t)(n0 + j) * M_ + m0 + i0 + vq * 8;
            if (outT)  *(uint4*)&outT[dst]  = o1.u4;
            if (outT1) *(uint4*)&outT1[dst] = o2.u4;
        }
    }
}

// ---------------- flash_a3v: a3v partials = softmax-chunks(q_l k^T) @ v, QBLK=256 ----------------
// One block owns ALL 256 q-rows of a bh (Q frags in registers, 4 subtiles/wave);
// 8 key-chunks of 512 for parallelism -> K/V each read exactly ONCE total.
// 64 MFMA per wave per barrier pair. fp32 partials + l, coalesced via LDS staging.
__global__ __launch_bounds__(256) void flash_a3v(const ushort_t* __restrict__ Q,
                                                 const ushort_t* __restrict__ K,
                                                 const ushort_t* __restrict__ V,
                                                 float* __restrict__ Opart,
                                                 float* __restrict__ lout) {
    const int nk = N_;
    const int CHUNK = N_ / 8;      // 512 keys
    int bh = blockIdx.y, ch = blockIdx.x;
    int j0 = ch * CHUNK, j1 = j0 + CHUNK;

    __shared__ __align__(16) ushort_t smem[4 * 64 * 72];
    ushort_t (*ks)[72]  = (ushort_t(*)[72])smem;
    ushort_t (*vts)[72] = (ushort_t(*)[72])(smem + 64 * 72);
    ushort_t (*pb)[64][72] = (ushort_t(*)[64][72])(smem + 2 * 64 * 72);

    int t = threadIdx.x;
    int w = t >> 6, lane = t & 63;
    int l15 = lane & 15, quad = lane >> 4, kq = quad * 8;
    int wrow = w * 16;

    // Q frags (256 rows) to registers via pb[0] staging (4 coalesced rounds)
    bfrag8 aq[4][2];
    const ushort_t* Qb = Q + (size_t)bh * M_ * DH_;
    #pragma unroll
    for (int s = 0; s < 4; s++) {
        #pragma unroll
        for (int u = 0; u < 2; u++) {
            int lin = t + 256 * u;
            int r = lin >> 3, cc = (lin & 7) * 8;
            *(uint4*)&pb[0][r][cc] = *(const uint4*)(Qb + (size_t)(s * 64 + r) * DH_ + cc);
        }
        __syncthreads();
        aq[s][0] = *(bfrag8*)&pb[0][wrow + l15][kq];
        aq[s][1] = *(bfrag8*)&pb[0][wrow + l15][32 + kq];
        __syncthreads();
    }

    fvec4 Oacc[4][4];
    #pragma unroll
    for (int s = 0; s < 4; s++)
        #pragma unroll
        for (int nt = 0; nt < 4; nt++)
            #pragma unroll
            for (int reg = 0; reg < 4; reg++) Oacc[s][nt][reg] = 0.f;
    float l_[4][4];
    #pragma unroll
    for (int s = 0; s < 4; s++)
        #pragma unroll
        for (int reg = 0; reg < 4; reg++) l_[s][reg] = 0.f;

    uint4 kreg[2], vreg[2];
    auto loadkv = [&](int j) {
        const ushort_t* Kb = K + ((size_t)bh * nk + j) * DH_;
        const ushort_t* Vb = V + ((size_t)bh * nk + j) * DH_;
        #pragma unroll
        for (int u = 0; u < 2; u++) {
            int lin = t + 256 * u;
            int r = lin >> 3, cc = (lin & 7) * 8;
            kreg[u] = *(const uint4*)(Kb + (size_t)r * DH_ + cc);
            vreg[u] = *(const uint4*)(Vb + (size_t)r * DH_ + cc);
        }
    };

    loadkv(j0);
    for (int j = j0; j < j1; j += 64) {
        #pragma unroll
        for (int u = 0; u < 2; u++) {
            int lin = t + 256 * u;
            int r = lin >> 3, cc = (lin & 7) * 8;
            *(uint4*)&ks[r][cc] = kreg[u];
            union { uint4 u4; ushort_t s[8]; } vv;
            vv.u4 = vreg[u];
            #pragma unroll
            for (int m = 0; m < 8; m++) vts[cc + m][r] = vv.s[m];
        }
        __syncthreads();
        if (j + 64 < j1) loadkv(j + 64);

        #pragma unroll
        for (int s = 0; s < 4; s++) {
            fvec4 S[4];
            #pragma unroll
            for (int ct = 0; ct < 4; ct++)
                #pragma unroll
                for (int reg = 0; reg < 4; reg++) S[ct][reg] = 0.f;
            #pragma unroll
            for (int ct = 0; ct < 4; ct++) {
                bfrag8 b0 = *(bfrag8*)&ks[ct * 16 + l15][kq];
                bfrag8 b1 = *(bfrag8*)&ks[ct * 16 + l15][32 + kq];
                S[ct] = __builtin_amdgcn_mfma_f32_16x16x32_bf16(aq[s][0], b0, S[ct], 0, 0, 0);
                S[ct] = __builtin_amdgcn_mfma_f32_16x16x32_bf16(aq[s][1], b1, S[ct], 0, 0, 0);
            }
            float ps[4] = {0.f, 0.f, 0.f, 0.f};
            #pragma unroll
            for (int ct = 0; ct < 4; ct++) {
                #pragma unroll
                for (int reg = 0; reg < 4; reg++) {
                    float pv = __expf(S[ct][reg]);
                    ps[reg] += pv;
                    pb[s & 1][wrow + quad * 4 + reg][ct * 16 + l15] = f2b(pv);
                }
            }
            #pragma unroll
            for (int reg = 0; reg < 4; reg++) {
                float sm = ps[reg];
                sm += __shfl_xor(sm, 1);
                sm += __shfl_xor(sm, 2);
                sm += __shfl_xor(sm, 4);
                sm += __shfl_xor(sm, 8);
                l_[s][reg] += sm;
            }
            bfrag8 ap0 = *(bfrag8*)&pb[s & 1][wrow + l15][kq];
            bfrag8 ap1 = *(bfrag8*)&pb[s & 1][wrow + l15][32 + kq];
            #pragma unroll
            for (int nt = 0; nt < 4; nt++) {
                bfrag8 v0 = *(bfrag8*)&vts[nt * 16 + l15][kq];
                bfrag8 v1 = *(bfrag8*)&vts[nt * 16 + l15][32 + kq];
                Oacc[s][nt] = __builtin_amdgcn_mfma_f32_16x16x32_bf16(ap0, v0, Oacc[s][nt], 0, 0, 0);
                Oacc[s][nt] = __builtin_amdgcn_mfma_f32_16x16x32_bf16(ap1, v1, Oacc[s][nt], 0, 0, 0);
            }
        }
        __syncthreads();
    }

    // epilogue: fp32 partials, coalesced via float staging (overlays ks+vts: 17408 <= 18432 B)
    float (*Of)[68] = (float(*)[68])smem;
    const size_t R = (size_t)BH_ * M_;
    size_t rowbase = (size_t)ch * R + (size_t)bh * M_;
    #pragma unroll
    for (int s = 0; s < 4; s++) {
        __syncthreads();
        #pragma unroll
        for (int reg = 0; reg < 4; reg++) {
            #pragma unroll
            for (int nt = 0; nt < 4; nt++)
                Of[wrow + quad * 4 + reg][nt * 16 + l15] = Oacc[s][nt][reg];
        }
        if (l15 == 0) {
            #pragma unroll
            for (int reg = 0; reg < 4; reg++)
                lout[rowbase + s * 64 + wrow + quad * 4 + reg] = l_[s][reg];
        }
        __syncthreads();
        int orow = t >> 2, oc = (t & 3) * 16;
        float* Od = Opart + (rowbase + s * 64 + orow) * DH_ + oc;
        #pragma unroll
        for (int i = 0; i < 4; i++) {
            float4 v4 = make_float4(Of[orow][oc + i * 4], Of[orow][oc + i * 4 + 1],
                                    Of[orow][oc + i * 4 + 2], Of[orow][oc + i * 4 + 3]);
            *(float4*)(Od + i * 4) = v4;
        }
    }
}

// combine 8 key-chunks -> a3v bf16 (no-max: plain sums)
__global__ __launch_bounds__(256) void flash_combine(const float* __restrict__ apart,
                                                     const float* __restrict__ lpart,
                                                     ushort_t* __restrict__ a3vb) {
    int idx = blockIdx.x * 256 + threadIdx.x;
    int d = idx & 63; int row = idx >> 6;
    const int R = BH_ * M_;
    size_t e = (size_t)row * DH_ + d;
    const size_t CH = (size_t)R * DH_;
    float l = 0.f, o = 0.f;
    #pragma unroll
    for (int s = 0; s < 8; s++) {
        l += lpart[row + (size_t)s * R];
        o += apart[e + (size_t)s * CH];
    }
    a3vb[e] = f2b(o / l);
}

// ---------------- flash_big: ctx = softmax(q kl^T) @ Wm, QBLK=256 ----------------
// Wave w, subtile s owns rows q0 + s*64 + w*16 (Q frags in registers).
// Per K-tile: 64 MFMA/wave between one barrier pair.
// K = kl [bh][256][64]; VT = WmT [bh][64][256]. Output bf16, coalesced.
__global__ __launch_bounds__(256) void flash_big(const ushort_t* __restrict__ Q,
                                                 const ushort_t* __restrict__ K,
                                                 const ushort_t* __restrict__ VT,
                                                 ushort_t* __restrict__ Obf) {
    const int nq = N_, nk = M_;
    int bh = blockIdx.y;
    int q0 = blockIdx.x * 256;
    __shared__ __align__(16) ushort_t ks[64][72];
    __shared__ __align__(16) ushort_t vts[64][72];
    __shared__ __align__(16) ushort_t pb[2][64][72];

    int t = threadIdx.x;
    int w = t >> 6, lane = t & 63;
    int l15 = lane & 15, quad = lane >> 4, kq = quad * 8;
    int wrow = w * 16;

    // ---- Q frags to registers via pb staging (4 coalesced rounds)
    bfrag8 aq[4][2];
    const ushort_t* Qb = Q + ((size_t)bh * nq + q0) * DH_;
    #pragma unroll
    for (int s = 0; s < 4; s++) {
        #pragma unroll
        for (int u = 0; u < 2; u++) {
            int lin = t + 256 * u;
            int r = lin >> 3, cc = (lin & 7) * 8;
            *(uint4*)&pb[0][r][cc] = *(const uint4*)(Qb + (size_t)(s * 64 + r) * DH_ + cc);
        }
        __syncthreads();
        aq[s][0] = *(bfrag8*)&pb[0][wrow + l15][kq];
        aq[s][1] = *(bfrag8*)&pb[0][wrow + l15][32 + kq];
        __syncthreads();
    }

    fvec4 Oacc[4][4];
    #pragma unroll
    for (int s = 0; s < 4; s++)
        #pragma unroll
        for (int nt = 0; nt < 4; nt++)
            #pragma unroll
            for (int reg = 0; reg < 4; reg++) Oacc[s][nt][reg] = 0.f;
    float l_[4][4];
    #pragma unroll
    for (int s = 0; s < 4; s++)
        #pragma unroll
        for (int reg = 0; reg < 4; reg++) l_[s][reg] = 0.f;

    const ushort_t* VTb = VT + (size_t)bh * DH_ * nk;
    uint4 kreg[2], vreg[2];
    auto loadkv = [&](int j) {
        const ushort_t* Kb = K + ((size_t)bh * nk + j) * DH_;
        #pragma unroll
        for (int u = 0; u < 2; u++) {
            int lin = t + 256 * u;
            int r = lin >> 3, cc = (lin & 7) * 8;
            kreg[u] = *(const uint4*)(Kb + (size_t)r * DH_ + cc);
            vreg[u] = *(const uint4*)(VTb + (size_t)r * nk + j + cc);
        }
    };

    loadkv(0);
    for (int j = 0; j < nk; j += 64) {
        #pragma unroll
        for (int u = 0; u < 2; u++) {
            int lin = t + 256 * u;
            int r = lin >> 3, cc = (lin & 7) * 8;
            *(uint4*)&ks[r][cc] = kreg[u];
            *(uint4*)&vts[r][cc] = vreg[u];
        }
        __syncthreads();
        if (j + 64 < nk) loadkv(j + 64);

        #pragma unroll
        for (int s = 0; s < 4; s++) {
            fvec4 S[4];
            #pragma unroll
            for (int ct = 0; ct < 4; ct++)
                #pragma unroll
                for (int reg = 0; reg < 4; reg++) S[ct][reg] = 0.f;
            #pragma unroll
            for (int ct = 0; ct < 4; ct++) {
                bfrag8 b0 = *(bfrag8*)&ks[ct * 16 + l15][kq];
                bfrag8 b1 = *(bfrag8*)&ks[ct * 16 + l15][32 + kq];
                S[ct] = __builtin_amdgcn_mfma_f32_16x16x32_bf16(aq[s][0], b0, S[ct], 0, 0, 0);
                S[ct] = __builtin_amdgcn_mfma_f32_16x16x32_bf16(aq[s][1], b1, S[ct], 0, 0, 0);
            }
            float ps[4] = {0.f, 0.f, 0.f, 0.f};
            #pragma unroll
            for (int ct = 0; ct < 4; ct++) {
                #pragma unroll
                for (int reg = 0; reg < 4; reg++) {
                    float pv = __expf(S[ct][reg]);
                    ps[reg] += pv;
                    pb[s & 1][wrow + quad * 4 + reg][ct * 16 + l15] = f2b(pv);
                }
            }
            #pragma unroll
            for (int reg = 0; reg < 4; reg++) {
                float sm = ps[reg];
                sm += __shfl_xor(sm, 1);
                sm += __shfl_xor(sm, 2);
                sm += __shfl_xor(sm, 4);
                sm += __shfl_xor(sm, 8);
                l_[s][reg] += sm;
            }
            bfrag8 ap0 = *(bfrag8*)&pb[s & 1][wrow + l15][kq];
            bfrag8 ap1 = *(bfrag8*)&pb[s & 1][wrow + l15][32 + kq];
            #pragma unroll
            for (int nt = 0; nt < 4; nt++) {
                bfrag8 v0 = *(bfrag8*)&vts[nt * 16 + l15][kq];
                bfrag8 v1 = *(bfrag8*)&vts[nt * 16 + l15][32 + kq];
                Oacc[s][nt] = __builtin_amdgcn_mfma_f32_16x16x32_bf16(ap0, v0, Oacc[s][nt], 0, 0, 0);
                Oacc[s][nt] = __builtin_amdgcn_mfma_f32_16x16x32_bf16(ap1, v1, Oacc[s][nt], 0, 0, 0);
            }
        }
        __syncthreads();
    }

    // epilogue: 4 rounds; round s stages rows q0+s*64..+63 in pb[0], coalesced store
    ushort_t* Ob = Obf + ((size_t)bh * nq + q0) * DH_;
    #pragma unroll
    for (int s = 0; s < 4; s++) {
        #pragma unroll
        for (int reg = 0; reg < 4; reg++) {
            float inv = 1.f / l_[s][reg];
            #pragma unroll
            for (int nt = 0; nt < 4; nt++)
                pb[0][wrow + quad * 4 + reg][nt * 16 + l15] = f2b(Oacc[s][nt][reg] * inv);
        }
        __syncthreads();
        #pragma unroll
        for (int u = 0; u < 2; u++) {
            int lin = t + 256 * u;
            int r = lin >> 3, i = (lin & 7) * 8;
            *(uint4*)(Ob + (size_t)(s * 64 + r) * DH_ + i) = *(uint4*)&pb[0][r][i];
        }
        __syncthreads();
    }
}

// ---------------- WmT = (z @ a3v)^T via MFMA ----------------
__global__ __launch_bounds__(256) void wm_mfma(const ushort_t* __restrict__ Z,
                                               const ushort_t* __restrict__ A3V,
                                               ushort_t* __restrict__ WmT) {
    __shared__ __align__(16) ushort_t As[64][72];
    __shared__ __align__(16) ushort_t Bs[64][72];
    int bh = blockIdx.y;
    int i0 = blockIdx.x * 64;
    const ushort_t* Zb = Z + ((size_t)bh << 16);
    const ushort_t* Ab = A3V + ((size_t)bh << 14);
    int t = threadIdx.x;
    int w = t >> 6, lane = t & 63;
    int wr = (w >> 1) * 32, wc = (w & 1) * 32;
    int l15 = lane & 15, quad = lane >> 4, kq = quad * 8;
    fvec4 acc[2][2] = {};
    int rbase = t >> 3, c8 = (t & 7) * 8;

    for (int kc = 0; kc < M_; kc += 64) {
        #pragma unroll
        for (int u = 0; u < 2; u++) {
            int rr = rbase + 32 * u;
            *(float4*)&Bs[rr][c8] = *(const float4*)(Zb + (size_t)(i0 + rr) * M_ + kc + c8);
            union { uint4 u4; ushort_t s[8]; } av;
            av.u4 = *(const uint4*)(Ab + (size_t)(kc + rr) * DH_ + c8);
            #pragma unroll
            for (int m = 0; m < 8; m++) As[c8 + m][rr] = av.s[m];
        }
        __syncthreads();
        #pragma unroll
        for (int ks = 0; ks < 64; ks += 32) {
            bfrag8 a[2], b[2];
            #pragma unroll
            for (int r = 0; r < 2; r++) a[r] = *(bfrag8*)&As[wr + r * 16 + l15][ks + kq];
            #pragma unroll
            for (int c = 0; c < 2; c++) b[c] = *(bfrag8*)&Bs[wc + c * 16 + l15][ks + kq];
            #pragma unroll
            for (int r = 0; r < 2; r++)
                #pragma unroll
                for (int c = 0; c < 2; c++)
                    acc[r][c] = __builtin_amdgcn_mfma_f32_16x16x32_bf16(a[r], b[c], acc[r][c], 0, 0, 0);
        }
        __syncthreads();
    }
    #pragma unroll
    for (int r = 0; r < 2; r++) {
        #pragma unroll
        for (int reg = 0; reg < 4; reg++) {
            int drow = wr + r * 16 + quad * 4 + reg;
            ushort_t* dp = WmT + ((size_t)bh * DH_ + drow) * M_;
            #pragma unroll
            for (int c = 0; c < 2; c++)
                dp[i0 + wc + c * 16 + l15] = f2b(acc[r][c][reg]);
        }
    }
}

// ---------------- conv residual: outh_bf = bf16(ctx_bf + conv(v)) ----------------
__global__ __launch_bounds__(256) void conv_kernel(const ushort_t* __restrict__ V,
                                                   const float* __restrict__ cw,
                                                   const ushort_t* __restrict__ ctxb,
                                                   ushort_t* __restrict__ outb) {
    int bh = blockIdx.y;
    int h = bh & 7;
    int i0 = blockIdx.x * 64;
    __shared__ float vb[96][64];
    __shared__ float wloc[33];
    int t = threadIdx.x;
    if (t < 33) wloc[t] = cw[h * 33 + t];
    #pragma unroll
    for (int u = 0; u < 3; u++) {
        int lin = t + 256 * u;
        int r = lin >> 3, cc = (lin & 7) * 8;
        int gi = i0 - 16 + r;
        union { uint4 u4; ushort_t s[8]; } val;
        if (gi >= 0 && gi < N_)
            val.u4 = *(const uint4*)(V + ((size_t)bh * N_ + gi) * DH_ + cc);
        else
            val.u4 = make_uint4(0, 0, 0, 0);
        #pragma unroll
        for (int m = 0; m < 8; m++) vb[r][cc + m] = b2f(val.s[m]);
    }
    __syncthreads();
    int d = t & 63, rb = t >> 6;
    for (int u = 0; u < 16; u++) {
        int r = rb * 16 + u;
        float s = 0.f;
        #pragma unroll
        for (int kk = 0; kk < 33; kk++) s += wloc[kk] * vb[r + kk][d];
        size_t o = ((size_t)bh * N_ + i0 + r) * DH_ + d;
        outb[o] = f2b(b2f(ctxb[o]) + s);
    }
}

extern "C" void kernel_launch(void* const* d_in, const int* in_sizes, int n_in,
                              void* d_out, int out_size, void* d_ws, size_t ws_size,
                              hipStream_t stream) {
    const float* x      = (const float*)d_in[0];
    const float* ln_w   = (const float*)d_in[1];
    const float* ln_b   = (const float*)d_in[2];
    const float* w_qkv  = (const float*)d_in[3];
    const float* w_out  = (const float*)d_in[4];
    const float* b_out  = (const float*)d_in[5];
    const float* conv_w = (const float*)d_in[6];
    const float* omega  = (const float*)d_in[7];
    float* out = (float*)d_out;

    // ---- workspace carve ----
    float* fp = (float*)d_ws;
    float* a2    = fp;              fp += SZ_MM;
    float* apart = fp;              fp += SZ_QKVH / 2;     // 8 chunks x BH*M*DH
    float* lpart = fp;              fp += 8 * BH_ * M_;
    float* cs2   = fp;              fp += 8 * BH_ * M_;
    ushort_t* us = (ushort_t*)fp;
    ushort_t* wqkvT = us;           us += DIM_ * 3 * DIM_;
    ushort_t* woT   = us;           us += DIM_ * DIM_;
    ushort_t* a2b   = us;           us += SZ_MM;
    ushort_t* zA    = us;           us += SZ_MM;
    ushort_t* zAT   = us;           us += SZ_MM;
    ushort_t* zB    = us;           us += SZ_MM;
    ushort_t* zBT   = us;           us += SZ_MM;
    ushort_t* qb    = us;           us += SZ_QKVH;
    ushort_t* kb    = us;           us += SZ_QKVH;
    ushort_t* vb    = us;           us += SZ_QKVH;
    ushort_t* ctxb  = us;           us += SZ_QKVH;       // pinv bf16 temps overlay (disjoint)
    ushort_t* outhb = us;           us += SZ_QKVH;       // aliased as nxb (disjoint lifetime)
    ushort_t* ql    = us;           us += SZ_LM;
    ushort_t* kl    = us;           us += SZ_LM;
    ushort_t* WmT   = us;           us += SZ_LM;
    ushort_t* a3vb  = us;           us += SZ_LM;
    unsigned* red   = (unsigned*)us;
    ushort_t* nxb = outhb;
    // pinv bf16 temporaries overlay ctxb (ctxb written only after pinv finishes)
    ushort_t* xz  = ctxb;
    ushort_t* t1T = xz  + SZ_MM;
    ushort_t* t2T = t1T + SZ_MM;
    ushort_t* t3T = t2T + SZ_MM;

    ln_kernel<<<B_ * N_, 256, 0, stream>>>(x, ln_w, ln_b, nxb);
    tcast<<<dim3(48, 16), 256, 0, stream>>>(w_qkv, wqkvT, DIM_, 3 * DIM_);
    tcast<<<dim3(16, 16), 256, 0, stream>>>(w_out, woT, DIM_, DIM_);
    gemm_bt128<0><<<dim3(12, 128), 256, 0, stream>>>(nxb, wqkvT, qb, kb, vb,
                                                     nullptr, nullptr, nullptr, nullptr);
    landmark_kernel<<<dim3(256, 2), 256, 0, stream>>>(qb, kb, ql, kl);
    sim2_softmax<<<dim3(M_, BH_), 256, 0, stream>>>(ql, kl, a2, a2b);
    zero2<<<1, 64, 0, stream>>>(red);
    colpart<<<dim3(BH_, 8), 256, 0, stream>>>(a2, cs2);
    colmax<<<BH_, 256, 0, stream>>>(cs2, red);
    pinv_init2<<<dim3(8, 8, 32), 256, 0, stream>>>(a2, red, zA, zAT);

    ushort_t* za = zA;  ushort_t* zaT = zAT;
    ushort_t* zb = zB;  ushort_t* zbT = zBT;
    for (int it = 0; it < 6; it++) {
        gemm_pinv<<<dim3(4, 4, BH_), 256, 0, stream>>>(a2b, zaT, xz, nullptr, t1T, nullptr, 0.f, 1.f);
        gemm_pinv<<<dim3(4, 4, BH_), 256, 0, stream>>>(xz, t1T, nullptr, t2T, nullptr, nullptr, 15.f, -1.f);
        gemm_pinv<<<dim3(4, 4, BH_), 256, 0, stream>>>(xz, t2T, nullptr, t3T, nullptr, nullptr, 13.f, -1.f);
        gemm_pinv<<<dim3(4, 4, BH_), 256, 0, stream>>>(za, t3T, zb, (it < 5) ? zbT : nullptr,
                                                       nullptr, nullptr, 0.f, 0.25f);
        ushort_t* tp;
        tp = za; za = zb; zb = tp;
        tp = zaT; zaT = zbT; zbT = tp;
    }
    // za now holds final z (bf16, normal layout)

    // a3v partials = softmax-chunks(q_l k^T) @ v  (QBLK=256, 8 key-chunks; K/V read once)
    flash_a3v<<<dim3(8, BH_), 256, 0, stream>>>(ql, kb, vb, apart, lpart);
    flash_combine<<<(BH_ * M_ * DH_) / 256, 256, 0, stream>>>(apart, lpart, a3vb);
    // WmT = (z @ a3v)^T  (bf16 MFMA)
    wm_mfma<<<dim3(4, BH_), 256, 0, stream>>>(za, a3vb, WmT);
    // ctxb = bf16( softmax(q kl^T) @ Wm )  — QBLK=256 flash
    flash_big<<<dim3(N_ / 256, BH_), 256, 0, stream>>>(qb, kl, WmT, ctxb);
    // outh = bf16(ctx + conv(v))
    conv_kernel<<<dim3(N_ / 64, BH_), 256, 0, stream>>>(vb, conv_w, ctxb, outhb);
    // out = omega*x + b_out + outh @ w_out
    gemm_bt128<1><<<dim3(4, 128), 256, 0, stream>>>(outhb, woT, nullptr, nullptr, nullptr,
                                                    x, b_out, omega, out);
}

// Round 9
// 478.387 us; speedup vs baseline: 1.0398x; 1.0398x over previous
//
#include <hip/hip_runtime.h>
#include <math.h>

#define B_    4
#define N_    4096
#define DIM_  512
#define H_    8
#define DH_   64
#define M_    256
#define LGRP  16
#define BH_   (B_*H_)
#define SCALE_ 0.125f
#define LN_EPS_ 1e-5f

#define SZ_QKVH (B_*H_*N_*DH_)   /* 8388608 */
#define SZ_LM   (BH_*M_*DH_)     /* 524288  */
#define SZ_MM   (BH_*M_*M_)      /* 2097152 */

typedef unsigned short ushort_t;
typedef __attribute__((ext_vector_type(8))) short bfrag8;
typedef __attribute__((ext_vector_type(4))) float fvec4;

__device__ __forceinline__ ushort_t f2b(float f) {
    unsigned u = __float_as_uint(f);
    unsigned r = (u + 0x7fffu + ((u >> 16) & 1u)) >> 16;
    return (ushort_t)r;
}
__device__ __forceinline__ float b2f(ushort_t s) {
    return __uint_as_float(((unsigned)s) << 16);
}

// async global->LDS DMA, 16B/lane; LDS dest = wave-uniform base + lane*16
__device__ __forceinline__ void gload16(const ushort_t* g, ushort_t* l) {
    __builtin_amdgcn_global_load_lds(
        (const __attribute__((address_space(1))) void*)g,
        (__attribute__((address_space(3))) void*)l, 16, 0, 0);
}

// ---------------- LayerNorm -> bf16 nx ----------------
__global__ __launch_bounds__(256) void ln_kernel(const float* __restrict__ x,
                                                 const float* __restrict__ w,
                                                 const float* __restrict__ bb,
                                                 ushort_t* __restrict__ nxb) {
    int row = blockIdx.x;
    int t = threadIdx.x;
    const float* xr = x + (size_t)row * DIM_;
    float v0 = xr[t], v1 = xr[t + 256];
    float s = v0 + v1, sq = v0 * v0 + v1 * v1;
    __shared__ float ls[4], lq[4];
    for (int off = 32; off > 0; off >>= 1) {
        s  += __shfl_down(s, off);
        sq += __shfl_down(sq, off);
    }
    int wid = t >> 6, lid = t & 63;
    if (lid == 0) { ls[wid] = s; lq[wid] = sq; }
    __syncthreads();
    if (t == 0) {
        float S = 0, Q = 0;
        for (int i = 0; i < 4; i++) { S += ls[i]; Q += lq[i]; }
        ls[0] = S; lq[0] = Q;
    }
    __syncthreads();
    float mean = ls[0] * (1.f / DIM_);
    float var  = lq[0] * (1.f / DIM_) - mean * mean;
    float rs = rsqrtf(var + LN_EPS_);
    ushort_t* o = nxb + (size_t)row * DIM_;
    o[t]       = f2b((v0 - mean) * rs * w[t]       + bb[t]);
    o[t + 256] = f2b((v1 - mean) * rs * w[t + 256] + bb[t + 256]);
}

// ---------------- transpose + cast fp32 [R][C] -> bf16 [C][R] ----------------
__global__ __launch_bounds__(256) void tcast(const float* __restrict__ in,
                                             ushort_t* __restrict__ outT,
                                             int R, int C) {
    __shared__ float tile[32][33];
    int c0 = blockIdx.x * 32, r0 = blockIdx.y * 32;
    int t = threadIdx.x;
    #pragma unroll
    for (int u = 0; u < 4; u++) {
        int lin = t + 256 * u;
        int r = lin >> 5, c = lin & 31;
        tile[r][c] = in[(size_t)(r0 + r) * C + c0 + c];
    }
    __syncthreads();
    #pragma unroll
    for (int u = 0; u < 4; u++) {
        int lin = t + 256 * u;
        int cc = lin >> 5, rr = lin & 31;
        outT[(size_t)(c0 + cc) * R + r0 + rr] = f2b(tile[rr][cc]);
    }
}

// ---------------- big MFMA GEMM: C[M][N] = A[M][512] @ BT[N][512]^T ----------------
// Dbuf global_load_lds + both-sides XOR swizzle + XCD-chunked block swizzle.
// EPI 0: qkv epilogue (bf16 q/k/v, LDS-coalesced). EPI 1: out = omega*x + bo + C.
template<int EPI>
__global__ __launch_bounds__(256) void gemm_bt128(const ushort_t* __restrict__ A,
                                                  const ushort_t* __restrict__ BT,
                                                  ushort_t* __restrict__ qb,
                                                  ushort_t* __restrict__ kb,
                                                  ushort_t* __restrict__ vb,
                                                  const float* __restrict__ x,
                                                  const float* __restrict__ bo,
                                                  const float* __restrict__ omega,
                                                  float* __restrict__ out) {
    const int K = 512;
    __shared__ __align__(16) ushort_t smem[4 * 128 * 64];   // 2 bufs x (A+B 128x64) = 64 KB
    int t = threadIdx.x;
    int lin = blockIdx.x + blockIdx.y * gridDim.x;
    int nwg = gridDim.x * gridDim.y;
    int wg  = (lin & 7) * (nwg >> 3) + (lin >> 3);
    int n0 = (wg % gridDim.x) * 128, m0 = (wg / gridDim.x) * 128;
    int w = t >> 6, lane = t & 63;
    int wr = (w >> 1) * 64, wc = (w & 1) * 64;
    int l15 = lane & 15, quad = lane >> 4, kq = quad * 8;
    int lrow = lane >> 3, lc8 = (lane & 7) * 8;
    int scol = lc8 ^ ((lrow & 7) << 3);     // source-side swizzle (elems)
    int sw   = (l15 & 7) << 3;              // read-side swizzle: row&7 == l15&7
    fvec4 acc[4][4] = {};

    auto stage = [&](int buf, int kc) {
        ushort_t* Ad = smem + buf * 16384;
        ushort_t* Bd = Ad + 8192;
        #pragma unroll
        for (int u = 0; u < 4; u++) {
            int r0 = (w << 5) + (u << 3);
            int row = r0 + lrow;
            const ushort_t* ga;
            if (EPI == 0) {
                ga = A + (size_t)(m0 + row) * K + kc + scol;
            } else {
                int grow = m0 + row; int b_ = grow >> 12, nn = grow & 4095;
                ga = A + (((size_t)(b_ * H_ + (kc >> 6)) * N_ + nn) << 6) + scol;
            }
            gload16(ga, Ad + r0 * 64);
            gload16(BT + (size_t)(n0 + row) * K + kc + scol, Bd + r0 * 64);
        }
    };

    stage(0, 0);
    __syncthreads();
    int cur = 0;
    for (int kt = 0; kt < 8; ++kt) {
        if (kt < 7) stage(cur ^ 1, (kt + 1) * 64);
        const ushort_t* As = smem + cur * 16384;
        const ushort_t* Bs = As + 8192;
        #pragma unroll
        for (int ks = 0; ks < 64; ks += 32) {
            int kcol = (ks + kq) ^ sw;
            bfrag8 a[4], b[4];
            #pragma unroll
            for (int r = 0; r < 4; r++) a[r] = *(bfrag8*)(As + (wr + r * 16 + l15) * 64 + kcol);
            #pragma unroll
            for (int c = 0; c < 4; c++) b[c] = *(bfrag8*)(Bs + (wc + c * 16 + l15) * 64 + kcol);
            #pragma unroll
            for (int r = 0; r < 4; r++)
                #pragma unroll
                for (int c = 0; c < 4; c++)
                    acc[r][c] = __builtin_amdgcn_mfma_f32_16x16x32_bf16(a[r], b[c], acc[r][c], 0, 0, 0);
        }
        __syncthreads();
        cur ^= 1;
    }

    if (EPI == 0) {
        int sec = n0 >> 9;                     // 0=q 1=k 2=v (tile never crosses)
        float mul = (sec == 0) ? SCALE_ : 1.0f;
        ushort_t (*Ct)[132] = (ushort_t(*)[132])smem;
        #pragma unroll
        for (int r = 0; r < 4; r++) {
            #pragma unroll
            for (int reg = 0; reg < 4; reg++) {
                int lr = wr + r * 16 + quad * 4 + reg;
                #pragma unroll
                for (int c = 0; c < 4; c++) {
                    int lc = wc + c * 16 + l15;
                    Ct[lr][lc] = f2b(acc[r][c][reg] * mul);
                }
            }
        }
        __syncthreads();
        int row = t & 127, half = t >> 7;
        int grow = m0 + row; int b_ = grow >> 12, nn = grow & 4095;
        int head = ((n0 & 511) >> 6) + half;
        ushort_t* dstbuf = (sec == 0) ? qb : ((sec == 1) ? kb : vb);
        ushort_t* dp = dstbuf + (((size_t)(b_ * H_ + head) * N_ + nn) << 6);
        #pragma unroll
        for (int i = 0; i < 8; i++)
            *(uint4*)(dp + i * 8) = *(uint4*)&Ct[row][half * 64 + i * 8];
    } else {
        float om = omega[0];
        #pragma unroll
        for (int r = 0; r < 4; r++) {
            #pragma unroll
            for (int reg = 0; reg < 4; reg++) {
                int grow = m0 + wr + r * 16 + quad * 4 + reg;
                #pragma unroll
                for (int c = 0; c < 4; c++) {
                    int gcol = n0 + wc + c * 16 + l15;
                    size_t o = (size_t)grow * DIM_ + gcol;
                    out[o] = om * x[o] + bo[gcol] + acc[r][c][reg];
                }
            }
        }
    }
}

// ---------------- landmark means (bf16 in/out, uint4 vectorized) ----------------
__global__ __launch_bounds__(256) void landmark_kernel(const ushort_t* __restrict__ q,
                                                       const ushort_t* __restrict__ k,
                                                       ushort_t* __restrict__ ql,
                                                       ushort_t* __restrict__ kl) {
    int idx = blockIdx.x * 256 + threadIdx.x;    // over SZ_LM/8 = 65536
    const ushort_t* src = blockIdx.y ? k : q;
    ushort_t* dst = blockIdx.y ? kl : ql;
    int d8 = (idx & 7) * 8;
    int m = (idx >> 3) & 255;
    int bh = idx >> 11;
    const ushort_t* p = src + (((size_t)bh * N_) + m * LGRP) * DH_ + d8;
    float s[8] = {};
    #pragma unroll
    for (int j = 0; j < LGRP; j++) {
        union { uint4 u4; ushort_t sv[8]; } val;
        val.u4 = *(const uint4*)(p + (size_t)j * DH_);
        #pragma unroll
        for (int e = 0; e < 8; e++) s[e] += b2f(val.sv[e]);
    }
    union { uint4 u4; ushort_t sv[8]; } o;
    #pragma unroll
    for (int e = 0; e < 8; e++) o.sv[e] = f2b(s[e] * (1.f / LGRP));
    *(uint4*)(dst + ((size_t)bh * M_ + m) * DH_ + d8) = o.u4;
}

// ---------------- sim2 + softmax -> a2 (fp32 + bf16) ----------------
__global__ __launch_bounds__(256) void sim2_softmax(const ushort_t* __restrict__ ql,
                                                    const ushort_t* __restrict__ kl,
                                                    float* __restrict__ a2,
                                                    ushort_t* __restrict__ a2b) {
    int i = blockIdx.x, bh = blockIdx.y, j = threadIdx.x;
    __shared__ float qrow[64];
    __shared__ float red[256];
    if (j < 64) qrow[j] = b2f(ql[((size_t)bh * M_ + i) * DH_ + j]);
    __syncthreads();
    const ushort_t* kr = kl + ((size_t)bh * M_ + j) * DH_;
    float s = 0;
    #pragma unroll
    for (int d = 0; d < 64; d++) s += qrow[d] * b2f(kr[d]);
    red[j] = s; __syncthreads();
    for (int off = 128; off > 0; off >>= 1) {
        if (j < off) red[j] = fmaxf(red[j], red[j + off]);
        __syncthreads();
    }
    float mx = red[0]; __syncthreads();
    float p = __expf(s - mx);
    red[j] = p; __syncthreads();
    for (int off = 128; off > 0; off >>= 1) {
        if (j < off) red[j] += red[j + off];
        __syncthreads();
    }
    float res = p / red[0];
    size_t o = ((size_t)bh * M_ + i) * M_ + j;
    a2[o] = res;
    a2b[o] = f2b(res);
}

// ---------------- pinv init scale: column sums (row sums of softmax == 1) ----------------
__global__ void zero2(unsigned* p) { if (threadIdx.x < 2) p[threadIdx.x] = 0u; }

__global__ __launch_bounds__(256) void colpart(const float* __restrict__ a2,
                                               float* __restrict__ cs2) {
    int bh = blockIdx.x, s = blockIdx.y, t = threadIdx.x;
    const float* A = a2 + ((size_t)bh << 16) + (size_t)s * 32 * M_;
    float cs = 0.f;
    #pragma unroll
    for (int i = 0; i < 32; i++) cs += A[(size_t)i * M_ + t];
    cs2[((size_t)s * BH_ + bh) * M_ + t] = cs;
}

__global__ __launch_bounds__(256) void colmax(const float* __restrict__ cs2, unsigned* red) {
    int bh = blockIdx.x, t = threadIdx.x;
    float v = 0.f;
    #pragma unroll
    for (int s = 0; s < 8; s++) v += cs2[((size_t)s * BH_ + bh) * M_ + t];
    __shared__ float lr[256];
    lr[t] = v; __syncthreads();
    for (int off = 128; off > 0; off >>= 1) {
        if (t < off) lr[t] = fmaxf(lr[t], lr[t + off]);
        __syncthreads();
    }
    if (t == 0) atomicMax(red, __float_as_uint(lr[0]));
}

__global__ __launch_bounds__(256) void pinv_init2(const float* __restrict__ a2,
                                                  const unsigned* __restrict__ red,
                                                  ushort_t* __restrict__ zA,
                                                  ushort_t* __restrict__ zAT) {
    __shared__ float tile[32][33];
    int bt = blockIdx.z; int j0 = blockIdx.x * 32, i0 = blockIdx.y * 32;
    float invd = 1.f / __uint_as_float(red[0]);
    const float* Ab = a2 + ((size_t)bt << 16);
    size_t bo = (size_t)bt << 16;
    int t = threadIdx.x;
    #pragma unroll
    for (int u = 0; u < 4; u++) {
        int lin = t + 256 * u; int r = lin >> 5, c = lin & 31;
        float vv = Ab[(size_t)(i0 + r) * M_ + j0 + c] * invd;
        tile[r][c] = vv;
        zAT[bo + (size_t)(i0 + r) * M_ + j0 + c] = f2b(vv);
    }
    __syncthreads();
    #pragma unroll
    for (int u = 0; u < 4; u++) {
        int lin = t + 256 * u; int cc = lin >> 5, rr = lin & 31;
        zA[bo + (size_t)(j0 + cc) * M_ + i0 + rr] = f2b(tile[rr][cc]);
    }
}

// ---------------- batched 256^3 MFMA gemm (64x64 tile, dbuf gload_lds + swizzle) ----------------
__global__ __launch_bounds__(256) void gemm_pinv(const ushort_t* __restrict__ A,
                                                 const ushort_t* __restrict__ BT,
                                                 ushort_t* __restrict__ outN,
                                                 ushort_t* __restrict__ outT,
                                                 ushort_t* __restrict__ outT1,
                                                 float* __restrict__ outF,
                                                 float coefI, float scale) {
    __shared__ __align__(16) ushort_t smem[2 * 8192];   // 2 bufs x (A+B 64x64) = 32 KB
    int t = threadIdx.x;
    int lin = blockIdx.x + (blockIdx.y << 2) + (blockIdx.z << 4);
    int wg  = (lin & 7) * 64 + (lin >> 3);
    int n0 = (wg & 3) * 64, m0 = ((wg >> 2) & 3) * 64;
    int bt = wg >> 4;
    const ushort_t* Ab = A + ((size_t)bt << 16);
    const ushort_t* Bb = BT + ((size_t)bt << 16);
    int w = t >> 6, lane = t & 63;
    int wr = (w >> 1) * 32, wc = (w & 1) * 32;
    int l15 = lane & 15, quad = lane >> 4, kq = quad * 8;
    int lrow = lane >> 3, lc8 = (lane & 7) * 8;
    int scol = lc8 ^ ((lrow & 7) << 3);
    int sw   = (l15 & 7) << 3;
    fvec4 acc[2][2] = {};

    auto stage = [&](int buf, int kc) {
        ushort_t* Ad = smem + buf * 8192;
        ushort_t* Bd = Ad + 4096;
        #pragma unroll
        for (int u = 0; u < 2; u++) {
            int r0 = (w << 4) + (u << 3);
            int row = r0 + lrow;
            gload16(Ab + (size_t)(m0 + row) * M_ + kc + scol, Ad + r0 * 64);
            gload16(Bb + (size_t)(n0 + row) * M_ + kc + scol, Bd + r0 * 64);
        }
    };

    stage(0, 0);
    __syncthreads();
    int cur = 0;
    for (int kt = 0; kt < 4; ++kt) {
        if (kt < 3) stage(cur ^ 1, (kt + 1) * 64);
        const ushort_t* As = smem + cur * 8192;
        const ushort_t* Bs = As + 4096;
        #pragma unroll
        for (int ks = 0; ks < 64; ks += 32) {
            int kcol = (ks + kq) ^ sw;
            bfrag8 a[2], b[2];
            #pragma unroll
            for (int r = 0; r < 2; r++) a[r] = *(bfrag8*)(As + (wr + r * 16 + l15) * 64 + kcol);
            #pragma unroll
            for (int c = 0; c < 2; c++) b[c] = *(bfrag8*)(Bs + (wc + c * 16 + l15) * 64 + kcol);
            #pragma unroll
            for (int r = 0; r < 2; r++)
                #pragma unroll
                for (int c = 0; c < 2; c++)
                    acc[r][c] = __builtin_amdgcn_mfma_f32_16x16x32_bf16(a[r], b[c], acc[r][c], 0, 0, 0);
        }
        __syncthreads();
        cur ^= 1;
    }

    size_t bto = (size_t)bt << 16;
    if (outN || outF) {
        #pragma unroll
        for (int r = 0; r < 2; r++) {
            #pragma unroll
            for (int reg = 0; reg < 4; reg++) {
                int grow = m0 + wr + r * 16 + quad * 4 + reg;
                #pragma unroll
                for (int c = 0; c < 2; c++) {
                    int gcol = n0 + wc + c * 16 + l15;
                    float cv = scale * acc[r][c][reg] + (grow == gcol ? coefI : 0.f);
                    if (outN) outN[bto + (size_t)grow * M_ + gcol] = f2b(cv);
                    if (outF) outF[bto + (size_t)grow * M_ + gcol] = cv;
                }
            }
        }
    }
    if (outT || outT1) {
        ushort_t (*Ct)[65] = (ushort_t(*)[65])&smem[0];
        #pragma unroll
        for (int r = 0; r < 2; r++) {
            #pragma unroll
            for (int reg = 0; reg < 4; reg++) {
                int lr = wr + r * 16 + quad * 4 + reg;
                #pragma unroll
                for (int c = 0; c < 2; c++) {
                    int lc = wc + c * 16 + l15;
                    float cv = scale * acc[r][c][reg] + ((m0 + lr) == (n0 + lc) ? coefI : 0.f);
                    Ct[lr][lc] = f2b(cv);
                }
            }
        }
        __syncthreads();
        int j = t & 63, quarter = t >> 6, i0 = quarter * 16;
        #pragma unroll
        for (int vq = 0; vq < 2; vq++) {
            union { uint4 u4; ushort_t s[8]; } o1, o2;
            #pragma unroll
            for (int e = 0; e < 8; e++) {
                int il = i0 + vq * 8 + e;
                ushort_t bv = Ct[il][j];
                o1.s[e] = bv;
                o2.s[e] = f2b(((m0 + il) == (n0 + j) ? 7.f : 0.f) - b2f(bv));
            }
            size_t dst = bto + (size_t)(n0 + j) * M_ + m0 + i0 + vq * 8;
            if (outT)  *(uint4*)&outT[dst]  = o1.u4;
            if (outT1) *(uint4*)&outT1[dst] = o2.u4;
        }
    }
}

// ---------------- flash_a3v: a3v partials = softmax-chunks(q_l k^T) @ v, QBLK=256 ----------------
// One block owns ALL 256 q-rows of a bh; 8 key-chunks -> K/V read once total.
// K/V LDS fragments hoisted to registers ONCE per K-tile, reused by all 4 subtiles
// (cuts per-K-tile LDS b128 reads 80 -> 24; flash kernels are LDS-pipe-bound).
__global__ __launch_bounds__(256) void flash_a3v(const ushort_t* __restrict__ Q,
                                                 const ushort_t* __restrict__ K,
                                                 const ushort_t* __restrict__ V,
                                                 float* __restrict__ Opart,
                                                 float* __restrict__ lout) {
    const int nk = N_;
    const int CHUNK = N_ / 8;      // 512 keys
    int bh = blockIdx.y, ch = blockIdx.x;
    int j0 = ch * CHUNK, j1 = j0 + CHUNK;

    __shared__ __align__(16) ushort_t smem[4 * 64 * 72];
    ushort_t (*ks)[72]  = (ushort_t(*)[72])smem;
    ushort_t (*vts)[72] = (ushort_t(*)[72])(smem + 64 * 72);
    ushort_t (*pb)[64][72] = (ushort_t(*)[64][72])(smem + 2 * 64 * 72);

    int t = threadIdx.x;
    int w = t >> 6, lane = t & 63;
    int l15 = lane & 15, quad = lane >> 4, kq = quad * 8;
    int wrow = w * 16;

    // Q frags (256 rows) to registers via pb[0] staging (4 coalesced rounds)
    bfrag8 aq[4][2];
    const ushort_t* Qb = Q + (size_t)bh * M_ * DH_;
    #pragma unroll
    for (int s = 0; s < 4; s++) {
        #pragma unroll
        for (int u = 0; u < 2; u++) {
            int lin = t + 256 * u;
            int r = lin >> 3, cc = (lin & 7) * 8;
            *(uint4*)&pb[0][r][cc] = *(const uint4*)(Qb + (size_t)(s * 64 + r) * DH_ + cc);
        }
        __syncthreads();
        aq[s][0] = *(bfrag8*)&pb[0][wrow + l15][kq];
        aq[s][1] = *(bfrag8*)&pb[0][wrow + l15][32 + kq];
        __syncthreads();
    }

    fvec4 Oacc[4][4];
    #pragma unroll
    for (int s = 0; s < 4; s++)
        #pragma unroll
        for (int nt = 0; nt < 4; nt++)
            #pragma unroll
            for (int reg = 0; reg < 4; reg++) Oacc[s][nt][reg] = 0.f;
    float l_[4][4];
    #pragma unroll
    for (int s = 0; s < 4; s++)
        #pragma unroll
        for (int reg = 0; reg < 4; reg++) l_[s][reg] = 0.f;

    uint4 kreg[2], vreg[2];
    auto loadkv = [&](int j) {
        const ushort_t* Kb = K + ((size_t)bh * nk + j) * DH_;
        const ushort_t* Vb = V + ((size_t)bh * nk + j) * DH_;
        #pragma unroll
        for (int u = 0; u < 2; u++) {
            int lin = t + 256 * u;
            int r = lin >> 3, cc = (lin & 7) * 8;
            kreg[u] = *(const uint4*)(Kb + (size_t)r * DH_ + cc);
            vreg[u] = *(const uint4*)(Vb + (size_t)r * DH_ + cc);
        }
    };

    loadkv(j0);
    for (int j = j0; j < j1; j += 64) {
        #pragma unroll
        for (int u = 0; u < 2; u++) {
            int lin = t + 256 * u;
            int r = lin >> 3, cc = (lin & 7) * 8;
            *(uint4*)&ks[r][cc] = kreg[u];
            union { uint4 u4; ushort_t s[8]; } vv;
            vv.u4 = vreg[u];
            #pragma unroll
            for (int m = 0; m < 8; m++) vts[cc + m][r] = vv.s[m];
        }
        __syncthreads();
        if (j + 64 < j1) loadkv(j + 64);

        // hoist K/V fragments once per K-tile (subtile-independent)
        bfrag8 kb0[4], kb1[4], vb0[4], vb1[4];
        #pragma unroll
        for (int ct = 0; ct < 4; ct++) {
            kb0[ct] = *(bfrag8*)&ks[ct * 16 + l15][kq];
            kb1[ct] = *(bfrag8*)&ks[ct * 16 + l15][32 + kq];
            vb0[ct] = *(bfrag8*)&vts[ct * 16 + l15][kq];
            vb1[ct] = *(bfrag8*)&vts[ct * 16 + l15][32 + kq];
        }

        #pragma unroll
        for (int s = 0; s < 4; s++) {
            fvec4 S[4];
            #pragma unroll
            for (int ct = 0; ct < 4; ct++)
                #pragma unroll
                for (int reg = 0; reg < 4; reg++) S[ct][reg] = 0.f;
            #pragma unroll
            for (int ct = 0; ct < 4; ct++) {
                S[ct] = __builtin_amdgcn_mfma_f32_16x16x32_bf16(aq[s][0], kb0[ct], S[ct], 0, 0, 0);
                S[ct] = __builtin_amdgcn_mfma_f32_16x16x32_bf16(aq[s][1], kb1[ct], S[ct], 0, 0, 0);
            }
            float ps[4] = {0.f, 0.f, 0.f, 0.f};
            #pragma unroll
            for (int ct = 0; ct < 4; ct++) {
                #pragma unroll
                for (int reg = 0; reg < 4; reg++) {
                    float pv = __expf(S[ct][reg]);
                    ps[reg] += pv;
                    pb[s & 1][wrow + quad * 4 + reg][ct * 16 + l15] = f2b(pv);
                }
            }
            #pragma unroll
            for (int reg = 0; reg < 4; reg++) {
                float sm = ps[reg];
                sm += __shfl_xor(sm, 1);
                sm += __shfl_xor(sm, 2);
                sm += __shfl_xor(sm, 4);
                sm += __shfl_xor(sm, 8);
                l_[s][reg] += sm;
            }
            bfrag8 ap0 = *(bfrag8*)&pb[s & 1][wrow + l15][kq];
            bfrag8 ap1 = *(bfrag8*)&pb[s & 1][wrow + l15][32 + kq];
            #pragma unroll
            for (int nt = 0; nt < 4; nt++) {
                Oacc[s][nt] = __builtin_amdgcn_mfma_f32_16x16x32_bf16(ap0, vb0[nt], Oacc[s][nt], 0, 0, 0);
                Oacc[s][nt] = __builtin_amdgcn_mfma_f32_16x16x32_bf16(ap1, vb1[nt], Oacc[s][nt], 0, 0, 0);
            }
        }
        __syncthreads();
    }

    // epilogue: fp32 partials, coalesced via float staging (overlays ks+vts)
    float (*Of)[68] = (float(*)[68])smem;
    const size_t R = (size_t)BH_ * M_;
    size_t rowbase = (size_t)ch * R + (size_t)bh * M_;
    #pragma unroll
    for (int s = 0; s < 4; s++) {
        __syncthreads();
        #pragma unroll
        for (int reg = 0; reg < 4; reg++) {
            #pragma unroll
            for (int nt = 0; nt < 4; nt++)
                Of[wrow + quad * 4 + reg][nt * 16 + l15] = Oacc[s][nt][reg];
        }
        if (l15 == 0) {
            #pragma unroll
            for (int reg = 0; reg < 4; reg++)
                lout[rowbase + s * 64 + wrow + quad * 4 + reg] = l_[s][reg];
        }
        __syncthreads();
        int orow = t >> 2, oc = (t & 3) * 16;
        float* Od = Opart + (rowbase + s * 64 + orow) * DH_ + oc;
        #pragma unroll
        for (int i = 0; i < 4; i++) {
            float4 v4 = make_float4(Of[orow][oc + i * 4], Of[orow][oc + i * 4 + 1],
                                    Of[orow][oc + i * 4 + 2], Of[orow][oc + i * 4 + 3]);
            *(float4*)(Od + i * 4) = v4;
        }
    }
}

// combine 8 key-chunks -> a3v bf16 (no-max: plain sums)
__global__ __launch_bounds__(256) void flash_combine(const float* __restrict__ apart,
                                                     const float* __restrict__ lpart,
                                                     ushort_t* __restrict__ a3vb) {
    int idx = blockIdx.x * 256 + threadIdx.x;
    int d = idx & 63; int row = idx >> 6;
    const int R = BH_ * M_;
    size_t e = (size_t)row * DH_ + d;
    const size_t CH = (size_t)R * DH_;
    float l = 0.f, o = 0.f;
    #pragma unroll
    for (int s = 0; s < 8; s++) {
        l += lpart[row + (size_t)s * R];
        o += apart[e + (size_t)s * CH];
    }
    a3vb[e] = f2b(o / l);
}

// ---------------- flash_big: ctx = softmax(q kl^T) @ Wm, QBLK=256 ----------------
// K/V fragments hoisted once per K-tile (reused by 4 subtiles) — see flash_a3v.
// K = kl [bh][256][64]; VT = WmT [bh][64][256]. Output bf16, coalesced.
__global__ __launch_bounds__(256) void flash_big(const ushort_t* __restrict__ Q,
                                                 const ushort_t* __restrict__ K,
                                                 const ushort_t* __restrict__ VT,
                                                 ushort_t* __restrict__ Obf) {
    const int nq = N_, nk = M_;
    int bh = blockIdx.y;
    int q0 = blockIdx.x * 256;
    __shared__ __align__(16) ushort_t ks[64][72];
    __shared__ __align__(16) ushort_t vts[64][72];
    __shared__ __align__(16) ushort_t pb[2][64][72];

    int t = threadIdx.x;
    int w = t >> 6, lane = t & 63;
    int l15 = lane & 15, quad = lane >> 4, kq = quad * 8;
    int wrow = w * 16;

    // ---- Q frags to registers via pb staging (4 coalesced rounds)
    bfrag8 aq[4][2];
    const ushort_t* Qb = Q + ((size_t)bh * nq + q0) * DH_;
    #pragma unroll
    for (int s = 0; s < 4; s++) {
        #pragma unroll
        for (int u = 0; u < 2; u++) {
            int lin = t + 256 * u;
            int r = lin >> 3, cc = (lin & 7) * 8;
            *(uint4*)&pb[0][r][cc] = *(const uint4*)(Qb + (size_t)(s * 64 + r) * DH_ + cc);
        }
        __syncthreads();
        aq[s][0] = *(bfrag8*)&pb[0][wrow + l15][kq];
        aq[s][1] = *(bfrag8*)&pb[0][wrow + l15][32 + kq];
        __syncthreads();
    }

    fvec4 Oacc[4][4];
    #pragma unroll
    for (int s = 0; s < 4; s++)
        #pragma unroll
        for (int nt = 0; nt < 4; nt++)
            #pragma unroll
            for (int reg = 0; reg < 4; reg++) Oacc[s][nt][reg] = 0.f;
    float l_[4][4];
    #pragma unroll
    for (int s = 0; s < 4; s++)
        #pragma unroll
        for (int reg = 0; reg < 4; reg++) l_[s][reg] = 0.f;

    const ushort_t* VTb = VT + (size_t)bh * DH_ * nk;
    uint4 kreg[2], vreg[2];
    auto loadkv = [&](int j) {
        const ushort_t* Kb = K + ((size_t)bh * nk + j) * DH_;
        #pragma unroll
        for (int u = 0; u < 2; u++) {
            int lin = t + 256 * u;
            int r = lin >> 3, cc = (lin & 7) * 8;
            kreg[u] = *(const uint4*)(Kb + (size_t)r * DH_ + cc);
            vreg[u] = *(const uint4*)(VTb + (size_t)r * nk + j + cc);
        }
    };

    loadkv(0);
    for (int j = 0; j < nk; j += 64) {
        #pragma unroll
        for (int u = 0; u < 2; u++) {
            int lin = t + 256 * u;
            int r = lin >> 3, cc = (lin & 7) * 8;
            *(uint4*)&ks[r][cc] = kreg[u];
            *(uint4*)&vts[r][cc] = vreg[u];
        }
        __syncthreads();
        if (j + 64 < nk) loadkv(j + 64);

        bfrag8 kb0[4], kb1[4], vb0[4], vb1[4];
        #pragma unroll
        for (int ct = 0; ct < 4; ct++) {
            kb0[ct] = *(bfrag8*)&ks[ct * 16 + l15][kq];
            kb1[ct] = *(bfrag8*)&ks[ct * 16 + l15][32 + kq];
            vb0[ct] = *(bfrag8*)&vts[ct * 16 + l15][kq];
            vb1[ct] = *(bfrag8*)&vts[ct * 16 + l15][32 + kq];
        }

        #pragma unroll
        for (int s = 0; s < 4; s++) {
            fvec4 S[4];
            #pragma unroll
            for (int ct = 0; ct < 4; ct++)
                #pragma unroll
                for (int reg = 0; reg < 4; reg++) S[ct][reg] = 0.f;
            #pragma unroll
            for (int ct = 0; ct < 4; ct++) {
                S[ct] = __builtin_amdgcn_mfma_f32_16x16x32_bf16(aq[s][0], kb0[ct], S[ct], 0, 0, 0);
                S[ct] = __builtin_amdgcn_mfma_f32_16x16x32_bf16(aq[s][1], kb1[ct], S[ct], 0, 0, 0);
            }
            float ps[4] = {0.f, 0.f, 0.f, 0.f};
            #pragma unroll
            for (int ct = 0; ct < 4; ct++) {
                #pragma unroll
                for (int reg = 0; reg < 4; reg++) {
                    float pv = __expf(S[ct][reg]);
                    ps[reg] += pv;
                    pb[s & 1][wrow + quad * 4 + reg][ct * 16 + l15] = f2b(pv);
                }
            }
            #pragma unroll
            for (int reg = 0; reg < 4; reg++) {
                float sm = ps[reg];
                sm += __shfl_xor(sm, 1);
                sm += __shfl_xor(sm, 2);
                sm += __shfl_xor(sm, 4);
                sm += __shfl_xor(sm, 8);
                l_[s][reg] += sm;
            }
            bfrag8 ap0 = *(bfrag8*)&pb[s & 1][wrow + l15][kq];
            bfrag8 ap1 = *(bfrag8*)&pb[s & 1][wrow + l15][32 + kq];
            #pragma unroll
            for (int nt = 0; nt < 4; nt++) {
                Oacc[s][nt] = __builtin_amdgcn_mfma_f32_16x16x32_bf16(ap0, vb0[nt], Oacc[s][nt], 0, 0, 0);
                Oacc[s][nt] = __builtin_amdgcn_mfma_f32_16x16x32_bf16(ap1, vb1[nt], Oacc[s][nt], 0, 0, 0);
            }
        }
        __syncthreads();
    }

    // epilogue: 4 rounds; round s stages rows q0+s*64..+63 in pb[0], coalesced store
    ushort_t* Ob = Obf + ((size_t)bh * nq + q0) * DH_;
    #pragma unroll
    for (int s = 0; s < 4; s++) {
        #pragma unroll
        for (int reg = 0; reg < 4; reg++) {
            float inv = 1.f / l_[s][reg];
            #pragma unroll
            for (int nt = 0; nt < 4; nt++)
                pb[0][wrow + quad * 4 + reg][nt * 16 + l15] = f2b(Oacc[s][nt][reg] * inv);
        }
        __syncthreads();
        #pragma unroll
        for (int u = 0; u < 2; u++) {
            int lin = t + 256 * u;
            int r = lin >> 3, i = (lin & 7) * 8;
            *(uint4*)(Ob + (size_t)(s * 64 + r) * DH_ + i) = *(uint4*)&pb[0][r][i];
        }
        __syncthreads();
    }
}

// ---------------- WmT = (z @ a3v)^T via MFMA ----------------
__global__ __launch_bounds__(256) void wm_mfma(const ushort_t* __restrict__ Z,
                                               const ushort_t* __restrict__ A3V,
                                               ushort_t* __restrict__ WmT) {
    __shared__ __align__(16) ushort_t As[64][72];
    __shared__ __align__(16) ushort_t Bs[64][72];
    int bh = blockIdx.y;
    int i0 = blockIdx.x * 64;
    const ushort_t* Zb = Z + ((size_t)bh << 16);
    const ushort_t* Ab = A3V + ((size_t)bh << 14);
    int t = threadIdx.x;
    int w = t >> 6, lane = t & 63;
    int wr = (w >> 1) * 32, wc = (w & 1) * 32;
    int l15 = lane & 15, quad = lane >> 4, kq = quad * 8;
    fvec4 acc[2][2] = {};
    int rbase = t >> 3, c8 = (t & 7) * 8;

    for (int kc = 0; kc < M_; kc += 64) {
        #pragma unroll
        for (int u = 0; u < 2; u++) {
            int rr = rbase + 32 * u;
            *(float4*)&Bs[rr][c8] = *(const float4*)(Zb + (size_t)(i0 + rr) * M_ + kc + c8);
            union { uint4 u4; ushort_t s[8]; } av;
            av.u4 = *(const uint4*)(Ab + (size_t)(kc + rr) * DH_ + c8);
            #pragma unroll
            for (int m = 0; m < 8; m++) As[c8 + m][rr] = av.s[m];
        }
        __syncthreads();
        #pragma unroll
        for (int ks = 0; ks < 64; ks += 32) {
            bfrag8 a[2], b[2];
            #pragma unroll
            for (int r = 0; r < 2; r++) a[r] = *(bfrag8*)&As[wr + r * 16 + l15][ks + kq];
            #pragma unroll
            for (int c = 0; c < 2; c++) b[c] = *(bfrag8*)&Bs[wc + c * 16 + l15][ks + kq];
            #pragma unroll
            for (int r = 0; r < 2; r++)
                #pragma unroll
                for (int c = 0; c < 2; c++)
                    acc[r][c] = __builtin_amdgcn_mfma_f32_16x16x32_bf16(a[r], b[c], acc[r][c], 0, 0, 0);
        }
        __syncthreads();
    }
    #pragma unroll
    for (int r = 0; r < 2; r++) {
        #pragma unroll
        for (int reg = 0; reg < 4; reg++) {
            int drow = wr + r * 16 + quad * 4 + reg;
            ushort_t* dp = WmT + ((size_t)bh * DH_ + drow) * M_;
            #pragma unroll
            for (int c = 0; c < 2; c++)
                dp[i0 + wc + c * 16 + l15] = f2b(acc[r][c][reg]);
        }
    }
}

// ---------------- conv residual: outh_bf = bf16(ctx_bf + conv(v)) ----------------
__global__ __launch_bounds__(256) void conv_kernel(const ushort_t* __restrict__ V,
                                                   const float* __restrict__ cw,
                                                   const ushort_t* __restrict__ ctxb,
                                                   ushort_t* __restrict__ outb) {
    int bh = blockIdx.y;
    int h = bh & 7;
    int i0 = blockIdx.x * 64;
    __shared__ float vb[96][64];
    __shared__ float wloc[33];
    int t = threadIdx.x;
    if (t < 33) wloc[t] = cw[h * 33 + t];
    #pragma unroll
    for (int u = 0; u < 3; u++) {
        int lin = t + 256 * u;
        int r = lin >> 3, cc = (lin & 7) * 8;
        int gi = i0 - 16 + r;
        union { uint4 u4; ushort_t s[8]; } val;
        if (gi >= 0 && gi < N_)
            val.u4 = *(const uint4*)(V + ((size_t)bh * N_ + gi) * DH_ + cc);
        else
            val.u4 = make_uint4(0, 0, 0, 0);
        #pragma unroll
        for (int m = 0; m < 8; m++) vb[r][cc + m] = b2f(val.s[m]);
    }
    __syncthreads();
    int d = t & 63, rb = t >> 6;
    for (int u = 0; u < 16; u++) {
        int r = rb * 16 + u;
        float s = 0.f;
        #pragma unroll
        for (int kk = 0; kk < 33; kk++) s += wloc[kk] * vb[r + kk][d];
        size_t o = ((size_t)bh * N_ + i0 + r) * DH_ + d;
        outb[o] = f2b(b2f(ctxb[o]) + s);
    }
}

extern "C" void kernel_launch(void* const* d_in, const int* in_sizes, int n_in,
                              void* d_out, int out_size, void* d_ws, size_t ws_size,
                              hipStream_t stream) {
    const float* x      = (const float*)d_in[0];
    const float* ln_w   = (const float*)d_in[1];
    const float* ln_b   = (const float*)d_in[2];
    const float* w_qkv  = (const float*)d_in[3];
    const float* w_out  = (const float*)d_in[4];
    const float* b_out  = (const float*)d_in[5];
    const float* conv_w = (const float*)d_in[6];
    const float* omega  = (const float*)d_in[7];
    float* out = (float*)d_out;

    // ---- workspace carve ----
    float* fp = (float*)d_ws;
    float* a2    = fp;              fp += SZ_MM;
    float* apart = fp;              fp += SZ_QKVH / 2;     // 8 chunks x BH*M*DH
    float* lpart = fp;              fp += 8 * BH_ * M_;
    float* cs2   = fp;              fp += 8 * BH_ * M_;
    ushort_t* us = (ushort_t*)fp;
    ushort_t* wqkvT = us;           us += DIM_ * 3 * DIM_;
    ushort_t* woT   = us;           us += DIM_ * DIM_;
    ushort_t* a2b   = us;           us += SZ_MM;
    ushort_t* zA    = us;           us += SZ_MM;
    ushort_t* zAT   = us;           us += SZ_MM;
    ushort_t* zB    = us;           us += SZ_MM;
    ushort_t* zBT   = us;           us += SZ_MM;
    ushort_t* qb    = us;           us += SZ_QKVH;
    ushort_t* kb    = us;           us += SZ_QKVH;
    ushort_t* vb    = us;           us += SZ_QKVH;
    ushort_t* ctxb  = us;           us += SZ_QKVH;       // pinv bf16 temps overlay (disjoint)
    ushort_t* outhb = us;           us += SZ_QKVH;       // aliased as nxb (disjoint lifetime)
    ushort_t* ql    = us;           us += SZ_LM;
    ushort_t* kl    = us;           us += SZ_LM;
    ushort_t* WmT   = us;           us += SZ_LM;
    ushort_t* a3vb  = us;           us += SZ_LM;
    unsigned* red   = (unsigned*)us;
    ushort_t* nxb = outhb;
    // pinv bf16 temporaries overlay ctxb (ctxb written only after pinv finishes)
    ushort_t* xz  = ctxb;
    ushort_t* t1T = xz  + SZ_MM;
    ushort_t* t2T = t1T + SZ_MM;
    ushort_t* t3T = t2T + SZ_MM;

    ln_kernel<<<B_ * N_, 256, 0, stream>>>(x, ln_w, ln_b, nxb);
    tcast<<<dim3(48, 16), 256, 0, stream>>>(w_qkv, wqkvT, DIM_, 3 * DIM_);
    tcast<<<dim3(16, 16), 256, 0, stream>>>(w_out, woT, DIM_, DIM_);
    gemm_bt128<0><<<dim3(12, 128), 256, 0, stream>>>(nxb, wqkvT, qb, kb, vb,
                                                     nullptr, nullptr, nullptr, nullptr);
    landmark_kernel<<<dim3(256, 2), 256, 0, stream>>>(qb, kb, ql, kl);
    sim2_softmax<<<dim3(M_, BH_), 256, 0, stream>>>(ql, kl, a2, a2b);
    zero2<<<1, 64, 0, stream>>>(red);
    colpart<<<dim3(BH_, 8), 256, 0, stream>>>(a2, cs2);
    colmax<<<BH_, 256, 0, stream>>>(cs2, red);
    pinv_init2<<<dim3(8, 8, 32), 256, 0, stream>>>(a2, red, zA, zAT);

    ushort_t* za = zA;  ushort_t* zaT = zAT;
    ushort_t* zb = zB;  ushort_t* zbT = zBT;
    for (int it = 0; it < 6; it++) {
        gemm_pinv<<<dim3(4, 4, BH_), 256, 0, stream>>>(a2b, zaT, xz, nullptr, t1T, nullptr, 0.f, 1.f);
        gemm_pinv<<<dim3(4, 4, BH_), 256, 0, stream>>>(xz, t1T, nullptr, t2T, nullptr, nullptr, 15.f, -1.f);
        gemm_pinv<<<dim3(4, 4, BH_), 256, 0, stream>>>(xz, t2T, nullptr, t3T, nullptr, nullptr, 13.f, -1.f);
        gemm_pinv<<<dim3(4, 4, BH_), 256, 0, stream>>>(za, t3T, zb, (it < 5) ? zbT : nullptr,
                                                       nullptr, nullptr, 0.f, 0.25f);
        ushort_t* tp;
        tp = za; za = zb; zb = tp;
        tp = zaT; zaT = zbT; zbT = tp;
    }
    // za now holds final z (bf16, normal layout)

    // a3v partials = softmax-chunks(q_l k^T) @ v  (QBLK=256, 8 key-chunks; K/V read once)
    flash_a3v<<<dim3(8, BH_), 256, 0, stream>>>(ql, kb, vb, apart, lpart);
    flash_combine<<<(BH_ * M_ * DH_) / 256, 256, 0, stream>>>(apart, lpart, a3vb);
    // WmT = (z @ a3v)^T  (bf16 MFMA)
    wm_mfma<<<dim3(4, BH_), 256, 0, stream>>>(za, a3vb, WmT);
    // ctxb = bf16( softmax(q kl^T) @ Wm )  — QBLK=256 flash
    flash_big<<<dim3(N_ / 256, BH_), 256, 0, stream>>>(qb, kl, WmT, ctxb);
    // outh = bf16(ctx + conv(v))
    conv_kernel<<<dim3(N_ / 64, BH_), 256, 0, stream>>>(vb, conv_w, ctxb, outhb);
    // out = omega*x + b_out + outh @ w_out
    gemm_bt128<1><<<dim3(4, 128), 256, 0, stream>>>(outhb, woT, nullptr, nullptr, nullptr,
                                                    x, b_out, omega, out);
}

// Round 10
// 471.723 us; speedup vs baseline: 1.0545x; 1.0141x over previous
//
#include <hip/hip_runtime.h>
#include <math.h>

#define B_    4
#define N_    4096
#define DIM_  512
#define H_    8
#define DH_   64
#define M_    256
#define LGRP  16
#define BH_   (B_*H_)
#define SCALE_ 0.125f
#define LN_EPS_ 1e-5f

#define SZ_QKVH (B_*H_*N_*DH_)   /* 8388608 */
#define SZ_LM   (BH_*M_*DH_)     /* 524288  */
#define SZ_MM   (BH_*M_*M_)      /* 2097152 */

typedef unsigned short ushort_t;
typedef __attribute__((ext_vector_type(8))) short bfrag8;
typedef __attribute__((ext_vector_type(4))) float fvec4;

__device__ __forceinline__ ushort_t f2b(float f) {
    unsigned u = __float_as_uint(f);
    unsigned r = (u + 0x7fffu + ((u >> 16) & 1u)) >> 16;
    return (ushort_t)r;
}
__device__ __forceinline__ float b2f(ushort_t s) {
    return __uint_as_float(((unsigned)s) << 16);
}

// async global->LDS DMA, 16B/lane; LDS dest = wave-uniform base + lane*16
__device__ __forceinline__ void gload16(const ushort_t* g, ushort_t* l) {
    __builtin_amdgcn_global_load_lds(
        (const __attribute__((address_space(1))) void*)g,
        (__attribute__((address_space(3))) void*)l, 16, 0, 0);
}

// ---------------- LayerNorm -> bf16 nx ----------------
__global__ __launch_bounds__(256) void ln_kernel(const float* __restrict__ x,
                                                 const float* __restrict__ w,
                                                 const float* __restrict__ bb,
                                                 ushort_t* __restrict__ nxb) {
    int row = blockIdx.x;
    int t = threadIdx.x;
    const float* xr = x + (size_t)row * DIM_;
    float v0 = xr[t], v1 = xr[t + 256];
    float s = v0 + v1, sq = v0 * v0 + v1 * v1;
    __shared__ float ls[4], lq[4];
    for (int off = 32; off > 0; off >>= 1) {
        s  += __shfl_down(s, off);
        sq += __shfl_down(sq, off);
    }
    int wid = t >> 6, lid = t & 63;
    if (lid == 0) { ls[wid] = s; lq[wid] = sq; }
    __syncthreads();
    if (t == 0) {
        float S = 0, Q = 0;
        for (int i = 0; i < 4; i++) { S += ls[i]; Q += lq[i]; }
        ls[0] = S; lq[0] = Q;
    }
    __syncthreads();
    float mean = ls[0] * (1.f / DIM_);
    float var  = lq[0] * (1.f / DIM_) - mean * mean;
    float rs = rsqrtf(var + LN_EPS_);
    ushort_t* o = nxb + (size_t)row * DIM_;
    o[t]       = f2b((v0 - mean) * rs * w[t]       + bb[t]);
    o[t + 256] = f2b((v1 - mean) * rs * w[t + 256] + bb[t + 256]);
}

// ---------------- transpose + cast fp32 [R][C] -> bf16 [C][R] ----------------
__global__ __launch_bounds__(256) void tcast(const float* __restrict__ in,
                                             ushort_t* __restrict__ outT,
                                             int R, int C) {
    __shared__ float tile[32][33];
    int c0 = blockIdx.x * 32, r0 = blockIdx.y * 32;
    int t = threadIdx.x;
    #pragma unroll
    for (int u = 0; u < 4; u++) {
        int lin = t + 256 * u;
        int r = lin >> 5, c = lin & 31;
        tile[r][c] = in[(size_t)(r0 + r) * C + c0 + c];
    }
    __syncthreads();
    #pragma unroll
    for (int u = 0; u < 4; u++) {
        int lin = t + 256 * u;
        int cc = lin >> 5, rr = lin & 31;
        outT[(size_t)(c0 + cc) * R + r0 + rr] = f2b(tile[rr][cc]);
    }
}

// ---------------- big MFMA GEMM: C[M][N] = A[M][512] @ BT[N][512]^T ----------------
// Dbuf global_load_lds + both-sides XOR swizzle + XCD-chunked block swizzle.
// EPI 0: qkv epilogue (bf16 q/k/v, LDS-coalesced). EPI 1: out = omega*x + bo + C.
template<int EPI>
__global__ __launch_bounds__(256) void gemm_bt128(const ushort_t* __restrict__ A,
                                                  const ushort_t* __restrict__ BT,
                                                  ushort_t* __restrict__ qb,
                                                  ushort_t* __restrict__ kb,
                                                  ushort_t* __restrict__ vb,
                                                  const float* __restrict__ x,
                                                  const float* __restrict__ bo,
                                                  const float* __restrict__ omega,
                                                  float* __restrict__ out) {
    const int K = 512;
    __shared__ __align__(16) ushort_t smem[4 * 128 * 64];   // 2 bufs x (A+B 128x64) = 64 KB
    int t = threadIdx.x;
    int lin = blockIdx.x + blockIdx.y * gridDim.x;
    int nwg = gridDim.x * gridDim.y;
    int wg  = (lin & 7) * (nwg >> 3) + (lin >> 3);
    int n0 = (wg % gridDim.x) * 128, m0 = (wg / gridDim.x) * 128;
    int w = t >> 6, lane = t & 63;
    int wr = (w >> 1) * 64, wc = (w & 1) * 64;
    int l15 = lane & 15, quad = lane >> 4, kq = quad * 8;
    int lrow = lane >> 3, lc8 = (lane & 7) * 8;
    int scol = lc8 ^ ((lrow & 7) << 3);     // source-side swizzle (elems)
    int sw   = (l15 & 7) << 3;              // read-side swizzle: row&7 == l15&7
    fvec4 acc[4][4] = {};

    auto stage = [&](int buf, int kc) {
        ushort_t* Ad = smem + buf * 16384;
        ushort_t* Bd = Ad + 8192;
        #pragma unroll
        for (int u = 0; u < 4; u++) {
            int r0 = (w << 5) + (u << 3);
            int row = r0 + lrow;
            const ushort_t* ga;
            if (EPI == 0) {
                ga = A + (size_t)(m0 + row) * K + kc + scol;
            } else {
                int grow = m0 + row; int b_ = grow >> 12, nn = grow & 4095;
                ga = A + (((size_t)(b_ * H_ + (kc >> 6)) * N_ + nn) << 6) + scol;
            }
            gload16(ga, Ad + r0 * 64);
            gload16(BT + (size_t)(n0 + row) * K + kc + scol, Bd + r0 * 64);
        }
    };

    stage(0, 0);
    __syncthreads();
    int cur = 0;
    for (int kt = 0; kt < 8; ++kt) {
        if (kt < 7) stage(cur ^ 1, (kt + 1) * 64);
        const ushort_t* As = smem + cur * 16384;
        const ushort_t* Bs = As + 8192;
        #pragma unroll
        for (int ks = 0; ks < 64; ks += 32) {
            int kcol = (ks + kq) ^ sw;
            bfrag8 a[4], b[4];
            #pragma unroll
            for (int r = 0; r < 4; r++) a[r] = *(bfrag8*)(As + (wr + r * 16 + l15) * 64 + kcol);
            #pragma unroll
            for (int c = 0; c < 4; c++) b[c] = *(bfrag8*)(Bs + (wc + c * 16 + l15) * 64 + kcol);
            #pragma unroll
            for (int r = 0; r < 4; r++)
                #pragma unroll
                for (int c = 0; c < 4; c++)
                    acc[r][c] = __builtin_amdgcn_mfma_f32_16x16x32_bf16(a[r], b[c], acc[r][c], 0, 0, 0);
        }
        __syncthreads();
        cur ^= 1;
    }

    if (EPI == 0) {
        int sec = n0 >> 9;                     // 0=q 1=k 2=v (tile never crosses)
        float mul = (sec == 0) ? SCALE_ : 1.0f;
        ushort_t (*Ct)[132] = (ushort_t(*)[132])smem;
        #pragma unroll
        for (int r = 0; r < 4; r++) {
            #pragma unroll
            for (int reg = 0; reg < 4; reg++) {
                int lr = wr + r * 16 + quad * 4 + reg;
                #pragma unroll
                for (int c = 0; c < 4; c++) {
                    int lc = wc + c * 16 + l15;
                    Ct[lr][lc] = f2b(acc[r][c][reg] * mul);
                }
            }
        }
        __syncthreads();
        int row = t & 127, half = t >> 7;
        int grow = m0 + row; int b_ = grow >> 12, nn = grow & 4095;
        int head = ((n0 & 511) >> 6) + half;
        ushort_t* dstbuf = (sec == 0) ? qb : ((sec == 1) ? kb : vb);
        ushort_t* dp = dstbuf + (((size_t)(b_ * H_ + head) * N_ + nn) << 6);
        #pragma unroll
        for (int i = 0; i < 8; i++)
            *(uint4*)(dp + i * 8) = *(uint4*)&Ct[row][half * 64 + i * 8];
    } else {
        float om = omega[0];
        #pragma unroll
        for (int r = 0; r < 4; r++) {
            #pragma unroll
            for (int reg = 0; reg < 4; reg++) {
                int grow = m0 + wr + r * 16 + quad * 4 + reg;
                #pragma unroll
                for (int c = 0; c < 4; c++) {
                    int gcol = n0 + wc + c * 16 + l15;
                    size_t o = (size_t)grow * DIM_ + gcol;
                    out[o] = om * x[o] + bo[gcol] + acc[r][c][reg];
                }
            }
        }
    }
}

// ---------------- landmark means (bf16 in/out, uint4 vectorized) ----------------
__global__ __launch_bounds__(256) void landmark_kernel(const ushort_t* __restrict__ q,
                                                       const ushort_t* __restrict__ k,
                                                       ushort_t* __restrict__ ql,
                                                       ushort_t* __restrict__ kl) {
    int idx = blockIdx.x * 256 + threadIdx.x;    // over SZ_LM/8 = 65536
    const ushort_t* src = blockIdx.y ? k : q;
    ushort_t* dst = blockIdx.y ? kl : ql;
    int d8 = (idx & 7) * 8;
    int m = (idx >> 3) & 255;
    int bh = idx >> 11;
    const ushort_t* p = src + (((size_t)bh * N_) + m * LGRP) * DH_ + d8;
    float s[8] = {};
    #pragma unroll
    for (int j = 0; j < LGRP; j++) {
        union { uint4 u4; ushort_t sv[8]; } val;
        val.u4 = *(const uint4*)(p + (size_t)j * DH_);
        #pragma unroll
        for (int e = 0; e < 8; e++) s[e] += b2f(val.sv[e]);
    }
    union { uint4 u4; ushort_t sv[8]; } o;
    #pragma unroll
    for (int e = 0; e < 8; e++) o.sv[e] = f2b(s[e] * (1.f / LGRP));
    *(uint4*)(dst + ((size_t)bh * M_ + m) * DH_ + d8) = o.u4;
}

// ---------------- sim2 + softmax -> a2 (fp32 + bf16) ----------------
__global__ __launch_bounds__(256) void sim2_softmax(const ushort_t* __restrict__ ql,
                                                    const ushort_t* __restrict__ kl,
                                                    float* __restrict__ a2,
                                                    ushort_t* __restrict__ a2b) {
    int i = blockIdx.x, bh = blockIdx.y, j = threadIdx.x;
    __shared__ float qrow[64];
    __shared__ float red[256];
    if (j < 64) qrow[j] = b2f(ql[((size_t)bh * M_ + i) * DH_ + j]);
    __syncthreads();
    const ushort_t* kr = kl + ((size_t)bh * M_ + j) * DH_;
    float s = 0;
    #pragma unroll
    for (int d = 0; d < 64; d++) s += qrow[d] * b2f(kr[d]);
    red[j] = s; __syncthreads();
    for (int off = 128; off > 0; off >>= 1) {
        if (j < off) red[j] = fmaxf(red[j], red[j + off]);
        __syncthreads();
    }
    float mx = red[0]; __syncthreads();
    float p = __expf(s - mx);
    red[j] = p; __syncthreads();
    for (int off = 128; off > 0; off >>= 1) {
        if (j < off) red[j] += red[j + off];
        __syncthreads();
    }
    float res = p / red[0];
    size_t o = ((size_t)bh * M_ + i) * M_ + j;
    a2[o] = res;
    a2b[o] = f2b(res);
}

// ---------------- pinv init scale: column sums (row sums of softmax == 1) ----------------
// partial column sums; block (0,0) thread 0 also zeroes the reduction cell
__global__ __launch_bounds__(256) void colpart(const float* __restrict__ a2,
                                               float* __restrict__ cs2,
                                               unsigned* __restrict__ red) {
    int bh = blockIdx.x, s = blockIdx.y, t = threadIdx.x;
    if (bh == 0 && s == 0 && t == 0) red[0] = 0u;
    const float* A = a2 + ((size_t)bh << 16) + (size_t)s * 32 * M_;
    float cs = 0.f;
    #pragma unroll
    for (int i = 0; i < 32; i++) cs += A[(size_t)i * M_ + t];
    cs2[((size_t)s * BH_ + bh) * M_ + t] = cs;
}

__global__ __launch_bounds__(256) void colmax(const float* __restrict__ cs2, unsigned* red) {
    int bh = blockIdx.x, t = threadIdx.x;
    float v = 0.f;
    #pragma unroll
    for (int s = 0; s < 8; s++) v += cs2[((size_t)s * BH_ + bh) * M_ + t];
    __shared__ float lr[256];
    lr[t] = v; __syncthreads();
    for (int off = 128; off > 0; off >>= 1) {
        if (t < off) lr[t] = fmaxf(lr[t], lr[t + off]);
        __syncthreads();
    }
    if (t == 0) atomicMax(red, __float_as_uint(lr[0]));
}

__global__ __launch_bounds__(256) void pinv_init2(const float* __restrict__ a2,
                                                  const unsigned* __restrict__ red,
                                                  ushort_t* __restrict__ zA,
                                                  ushort_t* __restrict__ zAT) {
    __shared__ float tile[32][33];
    int bt = blockIdx.z; int j0 = blockIdx.x * 32, i0 = blockIdx.y * 32;
    float invd = 1.f / __uint_as_float(red[0]);
    const float* Ab = a2 + ((size_t)bt << 16);
    size_t bo = (size_t)bt << 16;
    int t = threadIdx.x;
    #pragma unroll
    for (int u = 0; u < 4; u++) {
        int lin = t + 256 * u; int r = lin >> 5, c = lin & 31;
        float vv = Ab[(size_t)(i0 + r) * M_ + j0 + c] * invd;
        tile[r][c] = vv;
        zAT[bo + (size_t)(i0 + r) * M_ + j0 + c] = f2b(vv);
    }
    __syncthreads();
    #pragma unroll
    for (int u = 0; u < 4; u++) {
        int lin = t + 256 * u; int cc = lin >> 5, rr = lin & 31;
        zA[bo + (size_t)(j0 + cc) * M_ + i0 + rr] = f2b(tile[rr][cc]);
    }
}

// ---------------- batched 256^3 MFMA gemm: SINGLE-STAGE full-K ----------------
// Entire A/B 64x256 panels staged in one shot (chunked LDS [4][64][64] per matrix,
// 64 KB, same XOR swizzle). ONE vmcnt drain + barrier, then 64 uninterrupted
// MFMA/wave. Removes the 3 extra per-K-tile barrier-drain stalls of the dbuf loop.
// C = coefI*I + scale*(A @ BT^T); optional outputs:
//   outN = C (bf16)   outT = C^T (bf16)   outT1 = (7I-C)^T (bf16)   outF = C (fp32)
__global__ __launch_bounds__(256) void gemm_pinv(const ushort_t* __restrict__ A,
                                                 const ushort_t* __restrict__ BT,
                                                 ushort_t* __restrict__ outN,
                                                 ushort_t* __restrict__ outT,
                                                 ushort_t* __restrict__ outT1,
                                                 float* __restrict__ outF,
                                                 float coefI, float scale) {
    __shared__ __align__(16) ushort_t smem[2 * 16384];   // A[4][64][64] + B[4][64][64] = 64 KB
    int t = threadIdx.x;
    int lin = blockIdx.x + (blockIdx.y << 2) + (blockIdx.z << 4);
    int wg  = (lin & 7) * 64 + (lin >> 3);
    int n0 = (wg & 3) * 64, m0 = ((wg >> 2) & 3) * 64;
    int bt = wg >> 4;
    const ushort_t* Ab = A + ((size_t)bt << 16);
    const ushort_t* Bb = BT + ((size_t)bt << 16);
    int w = t >> 6, lane = t & 63;
    int wr = (w >> 1) * 32, wc = (w & 1) * 32;
    int l15 = lane & 15, quad = lane >> 4, kq = quad * 8;
    int lrow = lane >> 3, lc8 = (lane & 7) * 8;
    int scol = lc8 ^ ((lrow & 7) << 3);
    int sw   = (l15 & 7) << 3;
    fvec4 acc[2][2] = {};

    // stage ALL of K: 16 gload16/thread, one drain
    #pragma unroll
    for (int c = 0; c < 4; c++) {
        #pragma unroll
        for (int u = 0; u < 2; u++) {
            int r0 = (w << 4) + (u << 3);
            int row = r0 + lrow;
            gload16(Ab + (size_t)(m0 + row) * M_ + c * 64 + scol, smem + c * 4096 + r0 * 64);
            gload16(Bb + (size_t)(n0 + row) * M_ + c * 64 + scol, smem + 16384 + c * 4096 + r0 * 64);
        }
    }
    __syncthreads();

    #pragma unroll
    for (int ks = 0; ks < 256; ks += 32) {
        const ushort_t* As = smem + (ks >> 6) * 4096;
        const ushort_t* Bs = As + 16384;
        int kcol = ((ks & 63) + kq) ^ sw;
        bfrag8 a[2], b[2];
        #pragma unroll
        for (int r = 0; r < 2; r++) a[r] = *(bfrag8*)(As + (wr + r * 16 + l15) * 64 + kcol);
        #pragma unroll
        for (int c = 0; c < 2; c++) b[c] = *(bfrag8*)(Bs + (wc + c * 16 + l15) * 64 + kcol);
        #pragma unroll
        for (int r = 0; r < 2; r++)
            #pragma unroll
            for (int c = 0; c < 2; c++)
                acc[r][c] = __builtin_amdgcn_mfma_f32_16x16x32_bf16(a[r], b[c], acc[r][c], 0, 0, 0);
    }
    __syncthreads();

    size_t bto = (size_t)bt << 16;
    if (outN || outF) {
        #pragma unroll
        for (int r = 0; r < 2; r++) {
            #pragma unroll
            for (int reg = 0; reg < 4; reg++) {
                int grow = m0 + wr + r * 16 + quad * 4 + reg;
                #pragma unroll
                for (int c = 0; c < 2; c++) {
                    int gcol = n0 + wc + c * 16 + l15;
                    float cv = scale * acc[r][c][reg] + (grow == gcol ? coefI : 0.f);
                    if (outN) outN[bto + (size_t)grow * M_ + gcol] = f2b(cv);
                    if (outF) outF[bto + (size_t)grow * M_ + gcol] = cv;
                }
            }
        }
    }
    if (outT || outT1) {
        ushort_t (*Ct)[65] = (ushort_t(*)[65])&smem[0];
        #pragma unroll
        for (int r = 0; r < 2; r++) {
            #pragma unroll
            for (int reg = 0; reg < 4; reg++) {
                int lr = wr + r * 16 + quad * 4 + reg;
                #pragma unroll
                for (int c = 0; c < 2; c++) {
                    int lc = wc + c * 16 + l15;
                    float cv = scale * acc[r][c][reg] + ((m0 + lr) == (n0 + lc) ? coefI : 0.f);
                    Ct[lr][lc] = f2b(cv);
                }
            }
        }
        __syncthreads();
        int j = t & 63, quarter = t >> 6, i0 = quarter * 16;
        #pragma unroll
        for (int vq = 0; vq < 2; vq++) {
            union { uint4 u4; ushort_t s[8]; } o1, o2;
            #pragma unroll
            for (int e = 0; e < 8; e++) {
                int il = i0 + vq * 8 + e;
                ushort_t bv = Ct[il][j];
                o1.s[e] = bv;
                o2.s[e] = f2b(((m0 + il) == (n0 + j) ? 7.f : 0.f) - b2f(bv));
            }
            size_t dst = bto + (size_t)(n0 + j) * M_ + m0 + i0 + vq * 8;
            if (outT)  *(uint4*)&outT[dst]  = o1.u4;
            if (outT1) *(uint4*)&outT1[dst] = o2.u4;
        }
    }
}

// ---------------- flash_a3v: a3v partials = softmax-chunks(q_l k^T) @ v, QBLK=256 ----------------
// One block owns ALL 256 q-rows of a bh; 8 key-chunks -> K/V read once total.
// K/V LDS fragments hoisted to registers ONCE per K-tile, reused by all 4 subtiles.
__global__ __launch_bounds__(256) void flash_a3v(const ushort_t* __restrict__ Q,
                                                 const ushort_t* __restrict__ K,
                                                 const ushort_t* __restrict__ V,
                                                 float* __restrict__ Opart,
                                                 float* __restrict__ lout) {
    const int nk = N_;
    const int CHUNK = N_ / 8;      // 512 keys
    int bh = blockIdx.y, ch = blockIdx.x;
    int j0 = ch * CHUNK, j1 = j0 + CHUNK;

    __shared__ __align__(16) ushort_t smem[4 * 64 * 72];
    ushort_t (*ks)[72]  = (ushort_t(*)[72])smem;
    ushort_t (*vts)[72] = (ushort_t(*)[72])(smem + 64 * 72);
    ushort_t (*pb)[64][72] = (ushort_t(*)[64][72])(smem + 2 * 64 * 72);

    int t = threadIdx.x;
    int w = t >> 6, lane = t & 63;
    int l15 = lane & 15, quad = lane >> 4, kq = quad * 8;
    int wrow = w * 16;

    // Q frags (256 rows) to registers via pb[0] staging (4 coalesced rounds)
    bfrag8 aq[4][2];
    const ushort_t* Qb = Q + (size_t)bh * M_ * DH_;
    #pragma unroll
    for (int s = 0; s < 4; s++) {
        #pragma unroll
        for (int u = 0; u < 2; u++) {
            int lin = t + 256 * u;
            int r = lin >> 3, cc = (lin & 7) * 8;
            *(uint4*)&pb[0][r][cc] = *(const uint4*)(Qb + (size_t)(s * 64 + r) * DH_ + cc);
        }
        __syncthreads();
        aq[s][0] = *(bfrag8*)&pb[0][wrow + l15][kq];
        aq[s][1] = *(bfrag8*)&pb[0][wrow + l15][32 + kq];
        __syncthreads();
    }

    fvec4 Oacc[4][4];
    #pragma unroll
    for (int s = 0; s < 4; s++)
        #pragma unroll
        for (int nt = 0; nt < 4; nt++)
            #pragma unroll
            for (int reg = 0; reg < 4; reg++) Oacc[s][nt][reg] = 0.f;
    float l_[4][4];
    #pragma unroll
    for (int s = 0; s < 4; s++)
        #pragma unroll
        for (int reg = 0; reg < 4; reg++) l_[s][reg] = 0.f;

    uint4 kreg[2], vreg[2];
    auto loadkv = [&](int j) {
        const ushort_t* Kb = K + ((size_t)bh * nk + j) * DH_;
        const ushort_t* Vb = V + ((size_t)bh * nk + j) * DH_;
        #pragma unroll
        for (int u = 0; u < 2; u++) {
            int lin = t + 256 * u;
            int r = lin >> 3, cc = (lin & 7) * 8;
            kreg[u] = *(const uint4*)(Kb + (size_t)r * DH_ + cc);
            vreg[u] = *(const uint4*)(Vb + (size_t)r * DH_ + cc);
        }
    };

    loadkv(j0);
    for (int j = j0; j < j1; j += 64) {
        #pragma unroll
        for (int u = 0; u < 2; u++) {
            int lin = t + 256 * u;
            int r = lin >> 3, cc = (lin & 7) * 8;
            *(uint4*)&ks[r][cc] = kreg[u];
            union { uint4 u4; ushort_t s[8]; } vv;
            vv.u4 = vreg[u];
            #pragma unroll
            for (int m = 0; m < 8; m++) vts[cc + m][r] = vv.s[m];
        }
        __syncthreads();
        if (j + 64 < j1) loadkv(j + 64);

        // hoist K/V fragments once per K-tile (subtile-independent)
        bfrag8 kb0[4], kb1[4], vb0[4], vb1[4];
        #pragma unroll
        for (int ct = 0; ct < 4; ct++) {
            kb0[ct] = *(bfrag8*)&ks[ct * 16 + l15][kq];
            kb1[ct] = *(bfrag8*)&ks[ct * 16 + l15][32 + kq];
            vb0[ct] = *(bfrag8*)&vts[ct * 16 + l15][kq];
            vb1[ct] = *(bfrag8*)&vts[ct * 16 + l15][32 + kq];
        }

        #pragma unroll
        for (int s = 0; s < 4; s++) {
            fvec4 S[4];
            #pragma unroll
            for (int ct = 0; ct < 4; ct++)
                #pragma unroll
                for (int reg = 0; reg < 4; reg++) S[ct][reg] = 0.f;
            #pragma unroll
            for (int ct = 0; ct < 4; ct++) {
                S[ct] = __builtin_amdgcn_mfma_f32_16x16x32_bf16(aq[s][0], kb0[ct], S[ct], 0, 0, 0);
                S[ct] = __builtin_amdgcn_mfma_f32_16x16x32_bf16(aq[s][1], kb1[ct], S[ct], 0, 0, 0);
            }
            float ps[4] = {0.f, 0.f, 0.f, 0.f};
            #pragma unroll
            for (int ct = 0; ct < 4; ct++) {
                #pragma unroll
                for (int reg = 0; reg < 4; reg++) {
                    float pv = __expf(S[ct][reg]);
                    ps[reg] += pv;
                    pb[s & 1][wrow + quad * 4 + reg][ct * 16 + l15] = f2b(pv);
                }
            }
            #pragma unroll
            for (int reg = 0; reg < 4; reg++) {
                float sm = ps[reg];
                sm += __shfl_xor(sm, 1);
                sm += __shfl_xor(sm, 2);
                sm += __shfl_xor(sm, 4);
                sm += __shfl_xor(sm, 8);
                l_[s][reg] += sm;
            }
            bfrag8 ap0 = *(bfrag8*)&pb[s & 1][wrow + l15][kq];
            bfrag8 ap1 = *(bfrag8*)&pb[s & 1][wrow + l15][32 + kq];
            #pragma unroll
            for (int nt = 0; nt < 4; nt++) {
                Oacc[s][nt] = __builtin_amdgcn_mfma_f32_16x16x32_bf16(ap0, vb0[nt], Oacc[s][nt], 0, 0, 0);
                Oacc[s][nt] = __builtin_amdgcn_mfma_f32_16x16x32_bf16(ap1, vb1[nt], Oacc[s][nt], 0, 0, 0);
            }
        }
        __syncthreads();
    }

    // epilogue: fp32 partials, coalesced via float staging (overlays ks+vts)
    float (*Of)[68] = (float(*)[68])smem;
    const size_t R = (size_t)BH_ * M_;
    size_t rowbase = (size_t)ch * R + (size_t)bh * M_;
    #pragma unroll
    for (int s = 0; s < 4; s++) {
        __syncthreads();
        #pragma unroll
        for (int reg = 0; reg < 4; reg++) {
            #pragma unroll
            for (int nt = 0; nt < 4; nt++)
                Of[wrow + quad * 4 + reg][nt * 16 + l15] = Oacc[s][nt][reg];
        }
        if (l15 == 0) {
            #pragma unroll
            for (int reg = 0; reg < 4; reg++)
                lout[rowbase + s * 64 + wrow + quad * 4 + reg] = l_[s][reg];
        }
        __syncthreads();
        int orow = t >> 2, oc = (t & 3) * 16;
        float* Od = Opart + (rowbase + s * 64 + orow) * DH_ + oc;
        #pragma unroll
        for (int i = 0; i < 4; i++) {
            float4 v4 = make_float4(Of[orow][oc + i * 4], Of[orow][oc + i * 4 + 1],
                                    Of[orow][oc + i * 4 + 2], Of[orow][oc + i * 4 + 3]);
            *(float4*)(Od + i * 4) = v4;
        }
    }
}

// combine 8 key-chunks -> a3v bf16 (no-max: plain sums)
__global__ __launch_bounds__(256) void flash_combine(const float* __restrict__ apart,
                                                     const float* __restrict__ lpart,
                                                     ushort_t* __restrict__ a3vb) {
    int idx = blockIdx.x * 256 + threadIdx.x;
    int d = idx & 63; int row = idx >> 6;
    const int R = BH_ * M_;
    size_t e = (size_t)row * DH_ + d;
    const size_t CH = (size_t)R * DH_;
    float l = 0.f, o = 0.f;
    #pragma unroll
    for (int s = 0; s < 8; s++) {
        l += lpart[row + (size_t)s * R];
        o += apart[e + (size_t)s * CH];
    }
    a3vb[e] = f2b(o / l);
}

// ---------------- flash_big: ctx = softmax(q kl^T) @ Wm, QBLK=256 ----------------
// K/V fragments hoisted once per K-tile (reused by 4 subtiles) — see flash_a3v.
// K = kl [bh][256][64]; VT = WmT [bh][64][256]. Output bf16, coalesced.
__global__ __launch_bounds__(256) void flash_big(const ushort_t* __restrict__ Q,
                                                 const ushort_t* __restrict__ K,
                                                 const ushort_t* __restrict__ VT,
                                                 ushort_t* __restrict__ Obf) {
    const int nq = N_, nk = M_;
    int bh = blockIdx.y;
    int q0 = blockIdx.x * 256;
    __shared__ __align__(16) ushort_t ks[64][72];
    __shared__ __align__(16) ushort_t vts[64][72];
    __shared__ __align__(16) ushort_t pb[2][64][72];

    int t = threadIdx.x;
    int w = t >> 6, lane = t & 63;
    int l15 = lane & 15, quad = lane >> 4, kq = quad * 8;
    int wrow = w * 16;

    // ---- Q frags to registers via pb staging (4 coalesced rounds)
    bfrag8 aq[4][2];
    const ushort_t* Qb = Q + ((size_t)bh * nq + q0) * DH_;
    #pragma unroll
    for (int s = 0; s < 4; s++) {
        #pragma unroll
        for (int u = 0; u < 2; u++) {
            int lin = t + 256 * u;
            int r = lin >> 3, cc = (lin & 7) * 8;
            *(uint4*)&pb[0][r][cc] = *(const uint4*)(Qb + (size_t)(s * 64 + r) * DH_ + cc);
        }
        __syncthreads();
        aq[s][0] = *(bfrag8*)&pb[0][wrow + l15][kq];
        aq[s][1] = *(bfrag8*)&pb[0][wrow + l15][32 + kq];
        __syncthreads();
    }

    fvec4 Oacc[4][4];
    #pragma unroll
    for (int s = 0; s < 4; s++)
        #pragma unroll
        for (int nt = 0; nt < 4; nt++)
            #pragma unroll
            for (int reg = 0; reg < 4; reg++) Oacc[s][nt][reg] = 0.f;
    float l_[4][4];
    #pragma unroll
    for (int s = 0; s < 4; s++)
        #pragma unroll
        for (int reg = 0; reg < 4; reg++) l_[s][reg] = 0.f;

    const ushort_t* VTb = VT + (size_t)bh * DH_ * nk;
    uint4 kreg[2], vreg[2];
    auto loadkv = [&](int j) {
        const ushort_t* Kb = K + ((size_t)bh * nk + j) * DH_;
        #pragma unroll
        for (int u = 0; u < 2; u++) {
            int lin = t + 256 * u;
            int r = lin >> 3, cc = (lin & 7) * 8;
            kreg[u] = *(const uint4*)(Kb + (size_t)r * DH_ + cc);
            vreg[u] = *(const uint4*)(VTb + (size_t)r * nk + j + cc);
        }
    };

    loadkv(0);
    for (int j = 0; j < nk; j += 64) {
        #pragma unroll
        for (int u = 0; u < 2; u++) {
            int lin = t + 256 * u;
            int r = lin >> 3, cc = (lin & 7) * 8;
            *(uint4*)&ks[r][cc] = kreg[u];
            *(uint4*)&vts[r][cc] = vreg[u];
        }
        __syncthreads();
        if (j + 64 < nk) loadkv(j + 64);

        bfrag8 kb0[4], kb1[4], vb0[4], vb1[4];
        #pragma unroll
        for (int ct = 0; ct < 4; ct++) {
            kb0[ct] = *(bfrag8*)&ks[ct * 16 + l15][kq];
            kb1[ct] = *(bfrag8*)&ks[ct * 16 + l15][32 + kq];
            vb0[ct] = *(bfrag8*)&vts[ct * 16 + l15][kq];
            vb1[ct] = *(bfrag8*)&vts[ct * 16 + l15][32 + kq];
        }

        #pragma unroll
        for (int s = 0; s < 4; s++) {
            fvec4 S[4];
            #pragma unroll
            for (int ct = 0; ct < 4; ct++)
                #pragma unroll
                for (int reg = 0; reg < 4; reg++) S[ct][reg] = 0.f;
            #pragma unroll
            for (int ct = 0; ct < 4; ct++) {
                S[ct] = __builtin_amdgcn_mfma_f32_16x16x32_bf16(aq[s][0], kb0[ct], S[ct], 0, 0, 0);
                S[ct] = __builtin_amdgcn_mfma_f32_16x16x32_bf16(aq[s][1], kb1[ct], S[ct], 0, 0, 0);
            }
            float ps[4] = {0.f, 0.f, 0.f, 0.f};
            #pragma unroll
            for (int ct = 0; ct < 4; ct++) {
                #pragma unroll
                for (int reg = 0; reg < 4; reg++) {
                    float pv = __expf(S[ct][reg]);
                    ps[reg] += pv;
                    pb[s & 1][wrow + quad * 4 + reg][ct * 16 + l15] = f2b(pv);
                }
            }
            #pragma unroll
            for (int reg = 0; reg < 4; reg++) {
                float sm = ps[reg];
                sm += __shfl_xor(sm, 1);
                sm += __shfl_xor(sm, 2);
                sm += __shfl_xor(sm, 4);
                sm += __shfl_xor(sm, 8);
                l_[s][reg] += sm;
            }
            bfrag8 ap0 = *(bfrag8*)&pb[s & 1][wrow + l15][kq];
            bfrag8 ap1 = *(bfrag8*)&pb[s & 1][wrow + l15][32 + kq];
            #pragma unroll
            for (int nt = 0; nt < 4; nt++) {
                Oacc[s][nt] = __builtin_amdgcn_mfma_f32_16x16x32_bf16(ap0, vb0[nt], Oacc[s][nt], 0, 0, 0);
                Oacc[s][nt] = __builtin_amdgcn_mfma_f32_16x16x32_bf16(ap1, vb1[nt], Oacc[s][nt], 0, 0, 0);
            }
        }
        __syncthreads();
    }

    // epilogue: 4 rounds; round s stages rows q0+s*64..+63 in pb[0], coalesced store
    ushort_t* Ob = Obf + ((size_t)bh * nq + q0) * DH_;
    #pragma unroll
    for (int s = 0; s < 4; s++) {
        #pragma unroll
        for (int reg = 0; reg < 4; reg++) {
            float inv = 1.f / l_[s][reg];
            #pragma unroll
            for (int nt = 0; nt < 4; nt++)
                pb[0][wrow + quad * 4 + reg][nt * 16 + l15] = f2b(Oacc[s][nt][reg] * inv);
        }
        __syncthreads();
        #pragma unroll
        for (int u = 0; u < 2; u++) {
            int lin = t + 256 * u;
            int r = lin >> 3, i = (lin & 7) * 8;
            *(uint4*)(Ob + (size_t)(s * 64 + r) * DH_ + i) = *(uint4*)&pb[0][r][i];
        }
        __syncthreads();
    }
}

// ---------------- WmT = (z @ a3v)^T via MFMA ----------------
__global__ __launch_bounds__(256) void wm_mfma(const ushort_t* __restrict__ Z,
                                               const ushort_t* __restrict__ A3V,
                                               ushort_t* __restrict__ WmT) {
    __shared__ __align__(16) ushort_t As[64][72];
    __shared__ __align__(16) ushort_t Bs[64][72];
    int bh = blockIdx.y;
    int i0 = blockIdx.x * 64;
    const ushort_t* Zb = Z + ((size_t)bh << 16);
    const ushort_t* Ab = A3V + ((size_t)bh << 14);
    int t = threadIdx.x;
    int w = t >> 6, lane = t & 63;
    int wr = (w >> 1) * 32, wc = (w & 1) * 32;
    int l15 = lane & 15, quad = lane >> 4, kq = quad * 8;
    fvec4 acc[2][2] = {};
    int rbase = t >> 3, c8 = (t & 7) * 8;

    for (int kc = 0; kc < M_; kc += 64) {
        #pragma unroll
        for (int u = 0; u < 2; u++) {
            int rr = rbase + 32 * u;
            *(float4*)&Bs[rr][c8] = *(const float4*)(Zb + (size_t)(i0 + rr) * M_ + kc + c8);
            union { uint4 u4; ushort_t s[8]; } av;
            av.u4 = *(const uint4*)(Ab + (size_t)(kc + rr) * DH_ + c8);
            #pragma unroll
            for (int m = 0; m < 8; m++) As[c8 + m][rr] = av.s[m];
        }
        __syncthreads();
        #pragma unroll
        for (int ks = 0; ks < 64; ks += 32) {
            bfrag8 a[2], b[2];
            #pragma unroll
            for (int r = 0; r < 2; r++) a[r] = *(bfrag8*)&As[wr + r * 16 + l15][ks + kq];
            #pragma unroll
            for (int c = 0; c < 2; c++) b[c] = *(bfrag8*)&Bs[wc + c * 16 + l15][ks + kq];
            #pragma unroll
            for (int r = 0; r < 2; r++)
                #pragma unroll
                for (int c = 0; c < 2; c++)
                    acc[r][c] = __builtin_amdgcn_mfma_f32_16x16x32_bf16(a[r], b[c], acc[r][c], 0, 0, 0);
        }
        __syncthreads();
    }
    #pragma unroll
    for (int r = 0; r < 2; r++) {
        #pragma unroll
        for (int reg = 0; reg < 4; reg++) {
            int drow = wr + r * 16 + quad * 4 + reg;
            ushort_t* dp = WmT + ((size_t)bh * DH_ + drow) * M_;
            #pragma unroll
            for (int c = 0; c < 2; c++)
                dp[i0 + wc + c * 16 + l15] = f2b(acc[r][c][reg]);
        }
    }
}

// ---------------- conv residual: outh_bf = bf16(ctx_bf + conv(v)) ----------------
__global__ __launch_bounds__(256) void conv_kernel(const ushort_t* __restrict__ V,
                                                   const float* __restrict__ cw,
                                                   const ushort_t* __restrict__ ctxb,
                                                   ushort_t* __restrict__ outb) {
    int bh = blockIdx.y;
    int h = bh & 7;
    int i0 = blockIdx.x * 64;
    __shared__ float vb[96][64];
    __shared__ float wloc[33];
    int t = threadIdx.x;
    if (t < 33) wloc[t] = cw[h * 33 + t];
    #pragma unroll
    for (int u = 0; u < 3; u++) {
        int lin = t + 256 * u;
        int r = lin >> 3, cc = (lin & 7) * 8;
        int gi = i0 - 16 + r;
        union { uint4 u4; ushort_t s[8]; } val;
        if (gi >= 0 && gi < N_)
            val.u4 = *(const uint4*)(V + ((size_t)bh * N_ + gi) * DH_ + cc);
        else
            val.u4 = make_uint4(0, 0, 0, 0);
        #pragma unroll
        for (int m = 0; m < 8; m++) vb[r][cc + m] = b2f(val.s[m]);
    }
    __syncthreads();
    int d = t & 63, rb = t >> 6;
    for (int u = 0; u < 16; u++) {
        int r = rb * 16 + u;
        float s = 0.f;
        #pragma unroll
        for (int kk = 0; kk < 33; kk++) s += wloc[kk] * vb[r + kk][d];
        size_t o = ((size_t)bh * N_ + i0 + r) * DH_ + d;
        outb[o] = f2b(b2f(ctxb[o]) + s);
    }
}

extern "C" void kernel_launch(void* const* d_in, const int* in_sizes, int n_in,
                              void* d_out, int out_size, void* d_ws, size_t ws_size,
                              hipStream_t stream) {
    const float* x      = (const float*)d_in[0];
    const float* ln_w   = (const float*)d_in[1];
    const float* ln_b   = (const float*)d_in[2];
    const float* w_qkv  = (const float*)d_in[3];
    const float* w_out  = (const float*)d_in[4];
    const float* b_out  = (const float*)d_in[5];
    const float* conv_w = (const float*)d_in[6];
    const float* omega  = (const float*)d_in[7];
    float* out = (float*)d_out;

    // ---- workspace carve ----
    float* fp = (float*)d_ws;
    float* a2    = fp;              fp += SZ_MM;
    float* apart = fp;              fp += SZ_QKVH / 2;     // 8 chunks x BH*M*DH
    float* lpart = fp;              fp += 8 * BH_ * M_;
    float* cs2   = fp;              fp += 8 * BH_ * M_;
    ushort_t* us = (ushort_t*)fp;
    ushort_t* wqkvT = us;           us += DIM_ * 3 * DIM_;
    ushort_t* woT   = us;           us += DIM_ * DIM_;
    ushort_t* a2b   = us;           us += SZ_MM;
    ushort_t* zA    = us;           us += SZ_MM;
    ushort_t* zAT   = us;           us += SZ_MM;
    ushort_t* zB    = us;           us += SZ_MM;
    ushort_t* zBT   = us;           us += SZ_MM;
    ushort_t* qb    = us;           us += SZ_QKVH;
    ushort_t* kb    = us;           us += SZ_QKVH;
    ushort_t* vb    = us;           us += SZ_QKVH;
    ushort_t* ctxb  = us;           us += SZ_QKVH;       // pinv bf16 temps overlay (disjoint)
    ushort_t* outhb = us;           us += SZ_QKVH;       // aliased as nxb (disjoint lifetime)
    ushort_t* ql    = us;           us += SZ_LM;
    ushort_t* kl    = us;           us += SZ_LM;
    ushort_t* WmT   = us;           us += SZ_LM;
    ushort_t* a3vb  = us;           us += SZ_LM;
    unsigned* red   = (unsigned*)us;
    ushort_t* nxb = outhb;
    // pinv bf16 temporaries overlay ctxb (ctxb written only after pinv finishes)
    ushort_t* xz  = ctxb;
    ushort_t* t1T = xz  + SZ_MM;
    ushort_t* t2T = t1T + SZ_MM;
    ushort_t* t3T = t2T + SZ_MM;

    ln_kernel<<<B_ * N_, 256, 0, stream>>>(x, ln_w, ln_b, nxb);
    tcast<<<dim3(48, 16), 256, 0, stream>>>(w_qkv, wqkvT, DIM_, 3 * DIM_);
    tcast<<<dim3(16, 16), 256, 0, stream>>>(w_out, woT, DIM_, DIM_);
    gemm_bt128<0><<<dim3(12, 128), 256, 0, stream>>>(nxb, wqkvT, qb, kb, vb,
                                                     nullptr, nullptr, nullptr, nullptr);
    landmark_kernel<<<dim3(256, 2), 256, 0, stream>>>(qb, kb, ql, kl);
    sim2_softmax<<<dim3(M_, BH_), 256, 0, stream>>>(ql, kl, a2, a2b);
    colpart<<<dim3(BH_, 8), 256, 0, stream>>>(a2, cs2, red);
    colmax<<<BH_, 256, 0, stream>>>(cs2, red);
    pinv_init2<<<dim3(8, 8, 32), 256, 0, stream>>>(a2, red, zA, zAT);

    ushort_t* za = zA;  ushort_t* zaT = zAT;
    ushort_t* zb = zB;  ushort_t* zbT = zBT;
    for (int it = 0; it < 6; it++) {
        gemm_pinv<<<dim3(4, 4, BH_), 256, 0, stream>>>(a2b, zaT, xz, nullptr, t1T, nullptr, 0.f, 1.f);
        gemm_pinv<<<dim3(4, 4, BH_), 256, 0, stream>>>(xz, t1T, nullptr, t2T, nullptr, nullptr, 15.f, -1.f);
        gemm_pinv<<<dim3(4, 4, BH_), 256, 0, stream>>>(xz, t2T, nullptr, t3T, nullptr, nullptr, 13.f, -1.f);
        gemm_pinv<<<dim3(4, 4, BH_), 256, 0, stream>>>(za, t3T, zb, (it < 5) ? zbT : nullptr,
                                                       nullptr, nullptr, 0.f, 0.25f);
        ushort_t* tp;
        tp = za; za = zb; zb = tp;
        tp = zaT; zaT = zbT; zbT = tp;
    }
    // za now holds final z (bf16, normal layout)

    // a3v partials = softmax-chunks(q_l k^T) @ v  (QBLK=256, 8 key-chunks; K/V read once)
    flash_a3v<<<dim3(8, BH_), 256, 0, stream>>>(ql, kb, vb, apart, lpart);
    flash_combine<<<(BH_ * M_ * DH_) / 256, 256, 0, stream>>>(apart, lpart, a3vb);
    // WmT = (z @ a3v)^T  (bf16 MFMA)
    wm_mfma<<<dim3(4, BH_), 256, 0, stream>>>(za, a3vb, WmT);
    // ctxb = bf16( softmax(q kl^T) @ Wm )  — QBLK=256 flash
    flash_big<<<dim3(N_ / 256, BH_), 256, 0, stream>>>(qb, kl, WmT, ctxb);
    // outh = bf16(ctx + conv(v))
    conv_kernel<<<dim3(N_ / 64, BH_), 256, 0, stream>>>(vb, conv_w, ctxb, outhb);
    // out = omega*x + b_out + outh @ w_out
    gemm_bt128<1><<<dim3(4, 128), 256, 0, stream>>>(outhb, woT, nullptr, nullptr, nullptr,
                                                    x, b_out, omega, out);
}